// Round 1
// baseline (6337.902 us; speedup 1.0000x reference)
//
#include <hip/hip_runtime.h>
#include <math.h>

#define B_   8
#define NSEQ 1024
#define T_   (B_*NSEQ)     // 8192 tokens
#define DIN  64
#define D_   512
#define H_   8
#define HD_  64
#define FF_  2048
#define L_   6
#define C_   5

// ---------------------------------------------------------------------------
// GEMM: C[M,N] = A[M,K] @ W[N,K]^T + bias, optional ReLU.
// BM=128, BN=64, BK=16, 256 threads, 8x4 per-thread tile.
// LDS stored k-major (As[k][m], Ws[k][n]) so compute reads are float4.
// ---------------------------------------------------------------------------
template<bool RELU>
__global__ __launch_bounds__(256, 2)
void gemm_bias_kernel(const float* __restrict__ A, const float* __restrict__ W,
                      const float* __restrict__ bias, float* __restrict__ C,
                      int M, int N, int K)
{
    constexpr int BM = 128, BN = 64, BK = 16;
    __shared__ float As[BK][BM + 4];
    __shared__ float Ws[BK][BN + 4];
    const int tid = threadIdx.x;
    const int bm  = blockIdx.y * BM;
    const int bn  = blockIdx.x * BN;
    const int tm0 = (tid >> 4) * 4;   // 0..60 (rows tm0..+3 and tm0+64..+67)
    const int tn0 = (tid & 15) * 4;   // 0..60

    float acc[8][4];
    #pragma unroll
    for (int i = 0; i < 8; i++)
        #pragma unroll
        for (int j = 0; j < 4; j++) acc[i][j] = 0.f;

    for (int k0 = 0; k0 < K; k0 += BK) {
        // A tile: 128x16 floats = 512 float4 -> 2 per thread (transposed store)
        #pragma unroll
        for (int i = 0; i < 2; i++) {
            const int f  = tid + i*256;
            const int r  = f >> 2;
            const int kc = (f & 3) << 2;
            const float4 a4 = *(const float4*)(A + (size_t)(bm + r)*K + k0 + kc);
            As[kc+0][r] = a4.x; As[kc+1][r] = a4.y;
            As[kc+2][r] = a4.z; As[kc+3][r] = a4.w;
        }
        // W tile: 64x16 floats = 256 float4 -> 1 per thread
        {
            const int r  = tid >> 2;
            const int kc = (tid & 3) << 2;
            const float4 w4 = *(const float4*)(W + (size_t)(bn + r)*K + k0 + kc);
            Ws[kc+0][r] = w4.x; Ws[kc+1][r] = w4.y;
            Ws[kc+2][r] = w4.z; Ws[kc+3][r] = w4.w;
        }
        __syncthreads();
        #pragma unroll
        for (int kk = 0; kk < BK; kk++) {
            const float4 a0 = *(const float4*)&As[kk][tm0];
            const float4 a1 = *(const float4*)&As[kk][tm0 + 64];
            const float4 w0 = *(const float4*)&Ws[kk][tn0];
            const float af[8] = {a0.x,a0.y,a0.z,a0.w,a1.x,a1.y,a1.z,a1.w};
            const float wf[4] = {w0.x,w0.y,w0.z,w0.w};
            #pragma unroll
            for (int i = 0; i < 8; i++)
                #pragma unroll
                for (int j = 0; j < 4; j++)
                    acc[i][j] = fmaf(af[i], wf[j], acc[i][j]);
        }
        __syncthreads();
    }

    const float4 b4 = *(const float4*)(bias + bn + tn0);
    const float bsv[4] = {b4.x, b4.y, b4.z, b4.w};
    #pragma unroll
    for (int i = 0; i < 8; i++) {
        const int r = bm + tm0 + (i & 3) + ((i >> 2) << 6);
        float o[4];
        #pragma unroll
        for (int j = 0; j < 4; j++) {
            float t = acc[i][j] + bsv[j];
            if (RELU) t = fmaxf(t, 0.f);
            o[j] = t;
        }
        *(float4*)(C + (size_t)r*N + bn + tn0) = *(const float4*)o;
    }
}

// ---------------------------------------------------------------------------
// Flash-style attention, fp32. One block = 64 q-rows of one (b,h).
// Q,K,V,O layout: [(b*N + n)*D + h*64 + d]. 16x16 threads, 4x4 frags.
// Qs/Ks stored d-major (transposed) for float4 GEMM reads; V stored k-major.
// ---------------------------------------------------------------------------
__global__ __launch_bounds__(256)
void attn_kernel(const float* __restrict__ Q, const float* __restrict__ Kg,
                 const float* __restrict__ Vg, const unsigned char* __restrict__ mask,
                 float* __restrict__ O)
{
    __shared__ float Qs[64][68];   // [d][q], pre-scaled by 1/sqrt(HD)
    __shared__ float KVs[64][68];  // K phase: [d][k]; V phase: [k][d]
    __shared__ float Ps[64][68];   // [q][k]
    const int tid = threadIdx.x;
    const int b   = blockIdx.y >> 3;
    const int h   = blockIdx.y & 7;
    const int q0  = blockIdx.x * 64;
    const int tq  = tid >> 4;      // 0..15 -> q rows 4tq..4tq+3
    const int tk  = tid & 15;      // 0..15 -> k cols / d dims 4tk..4tk+3

    const float* Qbase = Q + ((size_t)(b*NSEQ + q0))*D_ + h*HD_;
    #pragma unroll
    for (int i = 0; i < 4; i++) {
        const int f  = tid + i*256;
        const int r  = f >> 4;
        const int d4 = (f & 15) << 2;
        const float4 v4 = *(const float4*)(Qbase + (size_t)r*D_ + d4);
        Qs[d4+0][r] = v4.x*0.125f; Qs[d4+1][r] = v4.y*0.125f;
        Qs[d4+2][r] = v4.z*0.125f; Qs[d4+3][r] = v4.w*0.125f;
    }

    float acc[4][4];
    #pragma unroll
    for (int i = 0; i < 4; i++)
        #pragma unroll
        for (int j = 0; j < 4; j++) acc[i][j] = 0.f;
    float mrow[4] = {-INFINITY, -INFINITY, -INFINITY, -INFINITY};
    float lrow[4] = {0.f, 0.f, 0.f, 0.f};
    const unsigned char* mp = mask + (size_t)b*NSEQ;

    for (int kt = 0; kt < NSEQ/64; kt++) {
        __syncthreads();   // Qs ready (iter 0) / prev PV readers done
        const float* Kbase = Kg + ((size_t)(b*NSEQ + kt*64))*D_ + h*HD_;
        #pragma unroll
        for (int i = 0; i < 4; i++) {
            const int f  = tid + i*256;
            const int r  = f >> 4;
            const int d4 = (f & 15) << 2;
            const float4 v4 = *(const float4*)(Kbase + (size_t)r*D_ + d4);
            KVs[d4+0][r] = v4.x; KVs[d4+1][r] = v4.y;
            KVs[d4+2][r] = v4.z; KVs[d4+3][r] = v4.w;
        }
        __syncthreads();

        // S tile: s[i][j] = q(4tq+i) . k(4tk+j)
        float s[4][4];
        #pragma unroll
        for (int i = 0; i < 4; i++)
            #pragma unroll
            for (int j = 0; j < 4; j++) s[i][j] = 0.f;
        #pragma unroll 16
        for (int d = 0; d < 64; d++) {
            const float4 qv = *(const float4*)&Qs[d][tq*4];
            const float4 kv = *(const float4*)&KVs[d][tk*4];
            const float qa[4] = {qv.x,qv.y,qv.z,qv.w};
            const float ka[4] = {kv.x,kv.y,kv.z,kv.w};
            #pragma unroll
            for (int i = 0; i < 4; i++)
                #pragma unroll
                for (int j = 0; j < 4; j++)
                    s[i][j] = fmaf(qa[i], ka[j], s[i][j]);
        }
        __syncthreads();   // K reads done; KVs reusable for V

        // V tile load (straight [k][d]) overlapped with softmax math
        const float* Vbase = Vg + ((size_t)(b*NSEQ + kt*64))*D_ + h*HD_;
        #pragma unroll
        for (int i = 0; i < 4; i++) {
            const int f  = tid + i*256;
            const int r  = f >> 4;
            const int d4 = (f & 15) << 2;
            *(float4*)&KVs[r][d4] = *(const float4*)(Vbase + (size_t)r*D_ + d4);
        }

        // key padding mask (all-false in this workload, kept for correctness)
        {
            const int kc = kt*64 + tk*4;
            #pragma unroll
            for (int j = 0; j < 4; j++)
                if (mp[kc + j]) {
                    #pragma unroll
                    for (int i = 0; i < 4; i++) s[i][j] = -INFINITY;
                }
        }

        // online softmax per q-row (row spread over 16 contiguous lanes)
        #pragma unroll
        for (int i = 0; i < 4; i++) {
            float tmax = fmaxf(fmaxf(s[i][0], s[i][1]), fmaxf(s[i][2], s[i][3]));
            #pragma unroll
            for (int off = 1; off < 16; off <<= 1)
                tmax = fmaxf(tmax, __shfl_xor(tmax, off, 16));
            const float mnew = fmaxf(mrow[i], tmax);
            float p[4];
            float rs = 0.f;
            #pragma unroll
            for (int j = 0; j < 4; j++) { p[j] = __expf(s[i][j] - mnew); rs += p[j]; }
            #pragma unroll
            for (int off = 1; off < 16; off <<= 1)
                rs += __shfl_xor(rs, off, 16);
            const float alpha = __expf(mrow[i] - mnew);
            lrow[i] = lrow[i]*alpha + rs;
            mrow[i] = mnew;
            #pragma unroll
            for (int j = 0; j < 4; j++) acc[i][j] *= alpha;
            *(float4*)&Ps[tq*4 + i][tk*4] = *(const float4*)p;
        }
        __syncthreads();   // V + P visible

        // O += P . V
        #pragma unroll 16
        for (int kk = 0; kk < 64; kk++) {
            const float4 vv = *(const float4*)&KVs[kk][tk*4];
            const float va[4] = {vv.x,vv.y,vv.z,vv.w};
            #pragma unroll
            for (int i = 0; i < 4; i++) {
                const float p = Ps[tq*4 + i][kk];
                #pragma unroll
                for (int j = 0; j < 4; j++)
                    acc[i][j] = fmaf(p, va[j], acc[i][j]);
            }
        }
    }

    float* Obase = O + ((size_t)(b*NSEQ + q0))*D_ + h*HD_;
    #pragma unroll
    for (int i = 0; i < 4; i++) {
        const float inv = 1.0f / lrow[i];
        float o[4];
        #pragma unroll
        for (int j = 0; j < 4; j++) o[j] = acc[i][j]*inv;
        *(float4*)(Obase + (size_t)(tq*4 + i)*D_ + tk*4) = *(const float4*)o;
    }
}

// ---------------------------------------------------------------------------
// Fused (x += delta); LayerNorm(x)*g + b, in place. One 128-thread block/row.
// delta == nullptr -> plain LN.
// ---------------------------------------------------------------------------
__global__ __launch_bounds__(128)
void add_ln_kernel(float* __restrict__ x, const float* __restrict__ delta,
                   const float* __restrict__ g, const float* __restrict__ bta)
{
    const int row = blockIdx.x;
    const int tid = threadIdx.x;
    float* xr = x + (size_t)row*D_;
    float4 xv = *(const float4*)(xr + tid*4);
    if (delta) {
        const float4 dv = *(const float4*)(delta + (size_t)row*D_ + tid*4);
        xv.x += dv.x; xv.y += dv.y; xv.z += dv.z; xv.w += dv.w;
    }
    float sum = xv.x + xv.y + xv.z + xv.w;
    float sq  = xv.x*xv.x + xv.y*xv.y + xv.z*xv.z + xv.w*xv.w;
    #pragma unroll
    for (int off = 1; off < 64; off <<= 1) {
        sum += __shfl_xor(sum, off, 64);
        sq  += __shfl_xor(sq,  off, 64);
    }
    __shared__ float red[2][2];
    if ((tid & 63) == 0) { red[tid >> 6][0] = sum; red[tid >> 6][1] = sq; }
    __syncthreads();
    sum = red[0][0] + red[1][0];
    sq  = red[0][1] + red[1][1];
    const float mu  = sum * (1.f/D_);
    const float var = sq * (1.f/D_) - mu*mu;
    const float rs  = rsqrtf(var + 1e-5f);
    const float4 gv = *(const float4*)(g   + tid*4);
    const float4 bv = *(const float4*)(bta + tid*4);
    float4 o;
    o.x = (xv.x - mu)*rs*gv.x + bv.x;
    o.y = (xv.y - mu)*rs*gv.y + bv.y;
    o.z = (xv.z - mu)*rs*gv.z + bv.z;
    o.w = (xv.w - mu)*rs*gv.w + bv.w;
    *(float4*)(xr + tid*4) = o;
}

// ---------------------------------------------------------------------------
// Head: logits[T,5] = x[T,512] @ head_W[5,512]^T + head_b. One wave per row.
// ---------------------------------------------------------------------------
__global__ __launch_bounds__(256)
void head_kernel(const float* __restrict__ x, const float* __restrict__ hw,
                 const float* __restrict__ hb, float* __restrict__ out)
{
    const int lane = threadIdx.x & 63;
    const int row  = blockIdx.x*4 + (threadIdx.x >> 6);
    const float* xr = x + (size_t)row*D_;
    float acc[C_] = {0.f,0.f,0.f,0.f,0.f};
    #pragma unroll
    for (int it = 0; it < D_/64; it++) {
        const int k0 = lane + it*64;
        const float xv = xr[k0];
        #pragma unroll
        for (int c = 0; c < C_; c++) acc[c] = fmaf(xv, hw[c*D_ + k0], acc[c]);
    }
    #pragma unroll
    for (int c = 0; c < C_; c++)
        #pragma unroll
        for (int off = 32; off; off >>= 1)
            acc[c] += __shfl_down(acc[c], off, 64);
    if (lane == 0) {
        #pragma unroll
        for (int c = 0; c < C_; c++) out[(size_t)row*C_ + c] = acc[c] + hb[c];
    }
}

// ---------------------------------------------------------------------------
extern "C" void kernel_launch(void* const* d_in, const int* in_sizes, int n_in,
                              void* d_out, int out_size, void* d_ws, size_t ws_size,
                              hipStream_t stream)
{
    const float* src     = (const float*)d_in[0];
    const unsigned char* kpm = (const unsigned char*)d_in[1];   // all-false bools
    const float* embed_W = (const float*)d_in[2];
    const float* embed_b = (const float*)d_in[3];
    const float* Wq = (const float*)d_in[4];
    const float* bq = (const float*)d_in[5];
    const float* Wk = (const float*)d_in[6];
    const float* bk = (const float*)d_in[7];
    const float* Wv = (const float*)d_in[8];
    const float* bv = (const float*)d_in[9];
    const float* Wo = (const float*)d_in[10];
    const float* bo = (const float*)d_in[11];
    const float* W1 = (const float*)d_in[12];
    const float* b1 = (const float*)d_in[13];
    const float* W2 = (const float*)d_in[14];
    const float* b2 = (const float*)d_in[15];
    const float* ln1_g = (const float*)d_in[16];
    const float* ln1_b = (const float*)d_in[17];
    const float* ln2_g = (const float*)d_in[18];
    const float* ln2_b = (const float*)d_in[19];
    const float* fin_g = (const float*)d_in[20];
    const float* fin_b = (const float*)d_in[21];
    const float* head_W = (const float*)d_in[22];
    const float* head_b = (const float*)d_in[23];
    float* out = (float*)d_out;

    float* ws = (float*)d_ws;
    const size_t S = (size_t)T_ * D_;
    float* x   = ws;
    float* q   = ws + 1*S;
    float* k   = ws + 2*S;
    float* v   = ws + 3*S;
    float* att = ws + 4*S;
    float* tmp = ws + 5*S;
    float* h1  = ws + 1*S;   // aliases q/k/v/att (dead by FF time): T_*FF_ = 4*S

    const dim3 blk(256);
    const dim3 gD (D_/64,  T_/128);   // N=512 GEMMs
    const dim3 gFF(FF_/64, T_/128);   // N=2048 GEMM

    // embed: x = src @ embed_W^T + embed_b   (K=64)
    gemm_bias_kernel<false><<<gD, blk, 0, stream>>>(src, embed_W, embed_b, x, T_, D_, DIN);

    for (int l = 0; l < L_; l++) {
        const float* wq = Wq + (size_t)l*D_*D_;  const float* bql = bq + (size_t)l*D_;
        const float* wk = Wk + (size_t)l*D_*D_;  const float* bkl = bk + (size_t)l*D_;
        const float* wv = Wv + (size_t)l*D_*D_;  const float* bvl = bv + (size_t)l*D_;
        const float* wo = Wo + (size_t)l*D_*D_;  const float* bol = bo + (size_t)l*D_;
        const float* w1 = W1 + (size_t)l*FF_*D_; const float* b1l = b1 + (size_t)l*FF_;
        const float* w2 = W2 + (size_t)l*D_*FF_; const float* b2l = b2 + (size_t)l*D_;

        gemm_bias_kernel<false><<<gD, blk, 0, stream>>>(x, wq, bql, q, T_, D_, D_);
        gemm_bias_kernel<false><<<gD, blk, 0, stream>>>(x, wk, bkl, k, T_, D_, D_);
        gemm_bias_kernel<false><<<gD, blk, 0, stream>>>(x, wv, bvl, v, T_, D_, D_);

        attn_kernel<<<dim3(NSEQ/64, B_*H_), blk, 0, stream>>>(q, k, v, kpm, att);

        gemm_bias_kernel<false><<<gD, blk, 0, stream>>>(att, wo, bol, tmp, T_, D_, D_);
        add_ln_kernel<<<T_, 128, 0, stream>>>(x, tmp, ln1_g + (size_t)l*D_, ln1_b + (size_t)l*D_);

        gemm_bias_kernel<true ><<<gFF, blk, 0, stream>>>(x, w1, b1l, h1, T_, FF_, D_);
        gemm_bias_kernel<false><<<gD, blk, 0, stream>>>(h1, w2, b2l, tmp, T_, D_, FF_);
        add_ln_kernel<<<T_, 128, 0, stream>>>(x, tmp, ln2_g + (size_t)l*D_, ln2_b + (size_t)l*D_);
    }

    add_ln_kernel<<<T_, 128, 0, stream>>>(x, nullptr, fin_g, fin_b);
    head_kernel<<<T_/4, 256, 0, stream>>>(x, head_W, head_b, out);
}

// Round 2
// 3015.309 us; speedup vs baseline: 2.1019x; 2.1019x over previous
//
#include <hip/hip_runtime.h>
#include <hip/hip_bf16.h>
#include <math.h>

#define B_   8
#define NSEQ 1024
#define T_   (B_*NSEQ)     // 8192 tokens
#define DIN  64
#define D_   512
#define H_   8
#define HD_  64
#define FF_  2048
#define L_   6
#define C_   5

typedef __attribute__((ext_vector_type(8))) short bf16x8;
typedef __attribute__((ext_vector_type(4))) float f32x4;

__device__ __forceinline__ unsigned short f2bf(float f) {
    __hip_bfloat16 h = __float2bfloat16(f);
    return *reinterpret_cast<unsigned short*>(&h);
}

__device__ __forceinline__ void gload_lds16(const void* g, void* l) {
    __builtin_amdgcn_global_load_lds(
        (const __attribute__((address_space(1))) unsigned int*)g,
        (__attribute__((address_space(3))) unsigned int*)l, 16, 0, 0);
}

// ---------------------------------------------------------------------------
// fp32 GEMM (kept for embed only, K=64): C = A @ W^T + bias
// ---------------------------------------------------------------------------
template<bool RELU>
__global__ __launch_bounds__(256, 2)
void gemm_bias_kernel(const float* __restrict__ A, const float* __restrict__ W,
                      const float* __restrict__ bias, float* __restrict__ C,
                      int M, int N, int K)
{
    constexpr int BM = 128, BN = 64, BK = 16;
    __shared__ float As[BK][BM + 4];
    __shared__ float Ws[BK][BN + 4];
    const int tid = threadIdx.x;
    const int bm  = blockIdx.y * BM;
    const int bn  = blockIdx.x * BN;
    const int tm0 = (tid >> 4) * 4;
    const int tn0 = (tid & 15) * 4;

    float acc[8][4];
    #pragma unroll
    for (int i = 0; i < 8; i++)
        #pragma unroll
        for (int j = 0; j < 4; j++) acc[i][j] = 0.f;

    for (int k0 = 0; k0 < K; k0 += BK) {
        #pragma unroll
        for (int i = 0; i < 2; i++) {
            const int f  = tid + i*256;
            const int r  = f >> 2;
            const int kc = (f & 3) << 2;
            const float4 a4 = *(const float4*)(A + (size_t)(bm + r)*K + k0 + kc);
            As[kc+0][r] = a4.x; As[kc+1][r] = a4.y;
            As[kc+2][r] = a4.z; As[kc+3][r] = a4.w;
        }
        {
            const int r  = tid >> 2;
            const int kc = (tid & 3) << 2;
            const float4 w4 = *(const float4*)(W + (size_t)(bn + r)*K + k0 + kc);
            Ws[kc+0][r] = w4.x; Ws[kc+1][r] = w4.y;
            Ws[kc+2][r] = w4.z; Ws[kc+3][r] = w4.w;
        }
        __syncthreads();
        #pragma unroll
        for (int kk = 0; kk < BK; kk++) {
            const float4 a0 = *(const float4*)&As[kk][tm0];
            const float4 a1 = *(const float4*)&As[kk][tm0 + 64];
            const float4 w0 = *(const float4*)&Ws[kk][tn0];
            const float af[8] = {a0.x,a0.y,a0.z,a0.w,a1.x,a1.y,a1.z,a1.w};
            const float wf[4] = {w0.x,w0.y,w0.z,w0.w};
            #pragma unroll
            for (int i = 0; i < 8; i++)
                #pragma unroll
                for (int j = 0; j < 4; j++)
                    acc[i][j] = fmaf(af[i], wf[j], acc[i][j]);
        }
        __syncthreads();
    }

    const float4 b4 = *(const float4*)(bias + bn + tn0);
    const float bsv[4] = {b4.x, b4.y, b4.z, b4.w};
    #pragma unroll
    for (int i = 0; i < 8; i++) {
        const int r = bm + tm0 + (i & 3) + ((i >> 2) << 6);
        float o[4];
        #pragma unroll
        for (int j = 0; j < 4; j++) {
            float t = acc[i][j] + bsv[j];
            if (RELU) t = fmaxf(t, 0.f);
            o[j] = t;
        }
        *(float4*)(C + (size_t)r*N + bn + tn0) = *(const float4*)o;
    }
}

// ---------------------------------------------------------------------------
// bf16 MFMA GEMM: C[M,N](f32 or bf16) = A[M,K]bf16 @ W[N,K]bf16^T + bias(f32)
// 128x128 tile, BK=64, 4 waves (2x2), 16x16x32 MFMA, 4x4 frags/wave.
// LDS linear [128][64]bf16; XOR-swizzle byte^=((row&7)<<4) applied on the
// global SOURCE address (inverse) and on ds_read (both-sides, rule #21).
// ---------------------------------------------------------------------------
template<bool RELU, bool OUT_BF16>
__global__ __launch_bounds__(256, 2)
void gemm_mfma_kernel(const unsigned short* __restrict__ A,
                      const unsigned short* __restrict__ W,
                      const float* __restrict__ bias,
                      void* __restrict__ Cout,
                      int M, int N, int K)
{
    constexpr int BM = 128, BN = 128, BK = 64;
    __shared__ short As[BM*BK];   // 16 KB, row-major [128][64]
    __shared__ short Bs[BN*BK];   // 16 KB
    const int tid = threadIdx.x;
    const int l   = tid & 63;
    const int wid = tid >> 6;          // 0..3
    const int wm  = wid >> 1, wn = wid & 1;
    const int bm  = blockIdx.y * BM;
    const int bn  = blockIdx.x * BN;

    // staging: chunk = 8 rows x 128 B; lane l -> row (l>>3), pre-swizzled col
    const int srow = l >> 3;                      // 0..7  (== row&7 always)
    const int scol = ((l & 7) ^ srow) * 8;        // elems, inverse-swizzled

    f32x4 acc[4][4];
    const f32x4 z = {0.f, 0.f, 0.f, 0.f};
    #pragma unroll
    for (int m = 0; m < 4; m++)
        #pragma unroll
        for (int n = 0; n < 4; n++) acc[m][n] = z;

    const int nk = K / BK;
    for (int kt = 0; kt < nk; kt++) {
        const int k0 = kt * BK;
        __syncthreads();   // prev iter's ds_reads done before overwrite
        #pragma unroll
        for (int c = 0; c < 4; c++) {
            const int r = wid*32 + c*8 + srow;    // 0..127
            gload_lds16(A + (size_t)(bm + r)*K + k0 + scol, &As[(wid*32 + c*8)*64]);
            gload_lds16(W + (size_t)(bn + r)*K + k0 + scol, &Bs[(wid*32 + c*8)*64]);
        }
        __syncthreads();   // vmcnt(0) drained by compiler before barrier

        #pragma unroll
        for (int h = 0; h < 2; h++) {
            bf16x8 af[4], bfr[4];
            #pragma unroll
            for (int m = 0; m < 4; m++) {
                const int R  = wm*64 + m*16 + (l & 15);
                const int cb = (h*64 + (l >> 4)*16) ^ ((R & 7) << 4);
                af[m] = *(const bf16x8*)((const char*)As + R*128 + cb);
            }
            #pragma unroll
            for (int n = 0; n < 4; n++) {
                const int Rc = wn*64 + n*16 + (l & 15);
                const int cb = (h*64 + (l >> 4)*16) ^ ((Rc & 7) << 4);
                bfr[n] = *(const bf16x8*)((const char*)Bs + Rc*128 + cb);
            }
            #pragma unroll
            for (int m = 0; m < 4; m++)
                #pragma unroll
                for (int n = 0; n < 4; n++)
                    acc[m][n] = __builtin_amdgcn_mfma_f32_16x16x32_bf16(af[m], bfr[n], acc[m][n], 0, 0, 0);
        }
    }

    // C/D layout: col = lane&15, row = (lane>>4)*4 + reg   [m89-verified]
    #pragma unroll
    for (int n = 0; n < 4; n++) {
        const int col = bn + wn*64 + n*16 + (l & 15);
        const float bv = bias[col];
        #pragma unroll
        for (int m = 0; m < 4; m++) {
            const int row0 = bm + wm*64 + m*16 + ((l >> 4) << 2);
            #pragma unroll
            for (int j = 0; j < 4; j++) {
                float t = acc[m][n][j] + bv;
                if (RELU) t = fmaxf(t, 0.f);
                if (OUT_BF16)
                    ((unsigned short*)Cout)[(size_t)(row0 + j)*N + col] = f2bf(t);
                else
                    ((float*)Cout)[(size_t)(row0 + j)*N + col] = t;
            }
        }
    }
}

// ---------------------------------------------------------------------------
// fp32 flash attention (unchanged from round 1)
// ---------------------------------------------------------------------------
__global__ __launch_bounds__(256)
void attn_kernel(const float* __restrict__ Q, const float* __restrict__ Kg,
                 const float* __restrict__ Vg, const unsigned char* __restrict__ mask,
                 float* __restrict__ O)
{
    __shared__ float Qs[64][68];
    __shared__ float KVs[64][68];
    __shared__ float Ps[64][68];
    const int tid = threadIdx.x;
    const int b   = blockIdx.y >> 3;
    const int h   = blockIdx.y & 7;
    const int q0  = blockIdx.x * 64;
    const int tq  = tid >> 4;
    const int tk  = tid & 15;

    const float* Qbase = Q + ((size_t)(b*NSEQ + q0))*D_ + h*HD_;
    #pragma unroll
    for (int i = 0; i < 4; i++) {
        const int f  = tid + i*256;
        const int r  = f >> 4;
        const int d4 = (f & 15) << 2;
        const float4 v4 = *(const float4*)(Qbase + (size_t)r*D_ + d4);
        Qs[d4+0][r] = v4.x*0.125f; Qs[d4+1][r] = v4.y*0.125f;
        Qs[d4+2][r] = v4.z*0.125f; Qs[d4+3][r] = v4.w*0.125f;
    }

    float acc[4][4];
    #pragma unroll
    for (int i = 0; i < 4; i++)
        #pragma unroll
        for (int j = 0; j < 4; j++) acc[i][j] = 0.f;
    float mrow[4] = {-INFINITY, -INFINITY, -INFINITY, -INFINITY};
    float lrow[4] = {0.f, 0.f, 0.f, 0.f};
    const unsigned char* mp = mask + (size_t)b*NSEQ;

    for (int kt = 0; kt < NSEQ/64; kt++) {
        __syncthreads();
        const float* Kbase = Kg + ((size_t)(b*NSEQ + kt*64))*D_ + h*HD_;
        #pragma unroll
        for (int i = 0; i < 4; i++) {
            const int f  = tid + i*256;
            const int r  = f >> 4;
            const int d4 = (f & 15) << 2;
            const float4 v4 = *(const float4*)(Kbase + (size_t)r*D_ + d4);
            KVs[d4+0][r] = v4.x; KVs[d4+1][r] = v4.y;
            KVs[d4+2][r] = v4.z; KVs[d4+3][r] = v4.w;
        }
        __syncthreads();

        float s[4][4];
        #pragma unroll
        for (int i = 0; i < 4; i++)
            #pragma unroll
            for (int j = 0; j < 4; j++) s[i][j] = 0.f;
        #pragma unroll 16
        for (int d = 0; d < 64; d++) {
            const float4 qv = *(const float4*)&Qs[d][tq*4];
            const float4 kv = *(const float4*)&KVs[d][tk*4];
            const float qa[4] = {qv.x,qv.y,qv.z,qv.w};
            const float ka[4] = {kv.x,kv.y,kv.z,kv.w};
            #pragma unroll
            for (int i = 0; i < 4; i++)
                #pragma unroll
                for (int j = 0; j < 4; j++)
                    s[i][j] = fmaf(qa[i], ka[j], s[i][j]);
        }
        __syncthreads();

        const float* Vbase = Vg + ((size_t)(b*NSEQ + kt*64))*D_ + h*HD_;
        #pragma unroll
        for (int i = 0; i < 4; i++) {
            const int f  = tid + i*256;
            const int r  = f >> 4;
            const int d4 = (f & 15) << 2;
            *(float4*)&KVs[r][d4] = *(const float4*)(Vbase + (size_t)r*D_ + d4);
        }

        {
            const int kc = kt*64 + tk*4;
            #pragma unroll
            for (int j = 0; j < 4; j++)
                if (mp[kc + j]) {
                    #pragma unroll
                    for (int i = 0; i < 4; i++) s[i][j] = -INFINITY;
                }
        }

        #pragma unroll
        for (int i = 0; i < 4; i++) {
            float tmax = fmaxf(fmaxf(s[i][0], s[i][1]), fmaxf(s[i][2], s[i][3]));
            #pragma unroll
            for (int off = 1; off < 16; off <<= 1)
                tmax = fmaxf(tmax, __shfl_xor(tmax, off, 16));
            const float mnew = fmaxf(mrow[i], tmax);
            float p[4];
            float rs = 0.f;
            #pragma unroll
            for (int j = 0; j < 4; j++) { p[j] = __expf(s[i][j] - mnew); rs += p[j]; }
            #pragma unroll
            for (int off = 1; off < 16; off <<= 1)
                rs += __shfl_xor(rs, off, 16);
            const float alpha = __expf(mrow[i] - mnew);
            lrow[i] = lrow[i]*alpha + rs;
            mrow[i] = mnew;
            #pragma unroll
            for (int j = 0; j < 4; j++) acc[i][j] *= alpha;
            *(float4*)&Ps[tq*4 + i][tk*4] = *(const float4*)p;
        }
        __syncthreads();

        #pragma unroll 16
        for (int kk = 0; kk < 64; kk++) {
            const float4 vv = *(const float4*)&KVs[kk][tk*4];
            const float va[4] = {vv.x,vv.y,vv.z,vv.w};
            #pragma unroll
            for (int i = 0; i < 4; i++) {
                const float p = Ps[tq*4 + i][kk];
                #pragma unroll
                for (int j = 0; j < 4; j++)
                    acc[i][j] = fmaf(p, va[j], acc[i][j]);
            }
        }
    }

    float* Obase = O + ((size_t)(b*NSEQ + q0))*D_ + h*HD_;
    #pragma unroll
    for (int i = 0; i < 4; i++) {
        const float inv = 1.0f / lrow[i];
        float o[4];
        #pragma unroll
        for (int j = 0; j < 4; j++) o[j] = acc[i][j]*inv;
        *(float4*)(Obase + (size_t)(tq*4 + i)*D_ + tk*4) = *(const float4*)o;
    }
}

// ---------------------------------------------------------------------------
// Fused (x += delta); LayerNorm(x)*g + b, in place.
// ---------------------------------------------------------------------------
__global__ __launch_bounds__(128)
void add_ln_kernel(float* __restrict__ x, const float* __restrict__ delta,
                   const float* __restrict__ g, const float* __restrict__ bta)
{
    const int row = blockIdx.x;
    const int tid = threadIdx.x;
    float* xr = x + (size_t)row*D_;
    float4 xv = *(const float4*)(xr + tid*4);
    if (delta) {
        const float4 dv = *(const float4*)(delta + (size_t)row*D_ + tid*4);
        xv.x += dv.x; xv.y += dv.y; xv.z += dv.z; xv.w += dv.w;
    }
    float sum = xv.x + xv.y + xv.z + xv.w;
    float sq  = xv.x*xv.x + xv.y*xv.y + xv.z*xv.z + xv.w*xv.w;
    #pragma unroll
    for (int off = 1; off < 64; off <<= 1) {
        sum += __shfl_xor(sum, off, 64);
        sq  += __shfl_xor(sq,  off, 64);
    }
    __shared__ float red[2][2];
    if ((tid & 63) == 0) { red[tid >> 6][0] = sum; red[tid >> 6][1] = sq; }
    __syncthreads();
    sum = red[0][0] + red[1][0];
    sq  = red[0][1] + red[1][1];
    const float mu  = sum * (1.f/D_);
    const float var = sq * (1.f/D_) - mu*mu;
    const float rs  = rsqrtf(var + 1e-5f);
    const float4 gv = *(const float4*)(g   + tid*4);
    const float4 bv = *(const float4*)(bta + tid*4);
    float4 o;
    o.x = (xv.x - mu)*rs*gv.x + bv.x;
    o.y = (xv.y - mu)*rs*gv.y + bv.y;
    o.z = (xv.z - mu)*rs*gv.z + bv.z;
    o.w = (xv.w - mu)*rs*gv.w + bv.w;
    *(float4*)(xr + tid*4) = o;
}

// ---------------------------------------------------------------------------
// Head: logits[T,5] = x[T,512] @ head_W[5,512]^T + head_b
// ---------------------------------------------------------------------------
__global__ __launch_bounds__(256)
void head_kernel(const float* __restrict__ x, const float* __restrict__ hw,
                 const float* __restrict__ hb, float* __restrict__ out)
{
    const int lane = threadIdx.x & 63;
    const int row  = blockIdx.x*4 + (threadIdx.x >> 6);
    const float* xr = x + (size_t)row*D_;
    float acc[C_] = {0.f,0.f,0.f,0.f,0.f};
    #pragma unroll
    for (int it = 0; it < D_/64; it++) {
        const int k0 = lane + it*64;
        const float xv = xr[k0];
        #pragma unroll
        for (int c = 0; c < C_; c++) acc[c] = fmaf(xv, hw[c*D_ + k0], acc[c]);
    }
    #pragma unroll
    for (int c = 0; c < C_; c++)
        #pragma unroll
        for (int off = 32; off; off >>= 1)
            acc[c] += __shfl_down(acc[c], off, 64);
    if (lane == 0) {
        #pragma unroll
        for (int c = 0; c < C_; c++) out[(size_t)row*C_ + c] = acc[c] + hb[c];
    }
}

// ---------------------------------------------------------------------------
// fp32 -> bf16 casts
// ---------------------------------------------------------------------------
__global__ __launch_bounds__(256)
void cast_bf16_kernel(const float* __restrict__ in, unsigned short* __restrict__ out, int n)
{
    const int i = (blockIdx.x*256 + threadIdx.x)*4;
    if (i < n) {
        const float4 v = *(const float4*)(in + i);
        ushort4 o;
        o.x = f2bf(v.x); o.y = f2bf(v.y); o.z = f2bf(v.z); o.w = f2bf(v.w);
        *(ushort4*)(out + i) = o;
    }
}

struct Cast6Args {
    const float* src[6];
    unsigned short* dst[6];
    int n[6];
};

__global__ __launch_bounds__(256)
void cast6_kernel(Cast6Args a)
{
    const int t = blockIdx.y;
    const int i = (blockIdx.x*256 + threadIdx.x)*4;
    if (i < a.n[t]) {
        const float4 v = *(const float4*)(a.src[t] + i);
        ushort4 o;
        o.x = f2bf(v.x); o.y = f2bf(v.y); o.z = f2bf(v.z); o.w = f2bf(v.w);
        *(ushort4*)(a.dst[t] + i) = o;
    }
}

// ---------------------------------------------------------------------------
extern "C" void kernel_launch(void* const* d_in, const int* in_sizes, int n_in,
                              void* d_out, int out_size, void* d_ws, size_t ws_size,
                              hipStream_t stream)
{
    const float* src     = (const float*)d_in[0];
    const unsigned char* kpm = (const unsigned char*)d_in[1];
    const float* embed_W = (const float*)d_in[2];
    const float* embed_b = (const float*)d_in[3];
    const float* Wq = (const float*)d_in[4];
    const float* bq = (const float*)d_in[5];
    const float* Wk = (const float*)d_in[6];
    const float* bk = (const float*)d_in[7];
    const float* Wv = (const float*)d_in[8];
    const float* bv = (const float*)d_in[9];
    const float* Wo = (const float*)d_in[10];
    const float* bo = (const float*)d_in[11];
    const float* W1 = (const float*)d_in[12];
    const float* b1 = (const float*)d_in[13];
    const float* W2 = (const float*)d_in[14];
    const float* b2 = (const float*)d_in[15];
    const float* ln1_g = (const float*)d_in[16];
    const float* ln1_b = (const float*)d_in[17];
    const float* ln2_g = (const float*)d_in[18];
    const float* ln2_b = (const float*)d_in[19];
    const float* fin_g = (const float*)d_in[20];
    const float* fin_b = (const float*)d_in[21];
    const float* head_W = (const float*)d_in[22];
    const float* head_b = (const float*)d_in[23];
    float* out = (float*)d_out;

    float* ws = (float*)d_ws;
    const size_t S = (size_t)T_ * D_;         // 4,194,304 floats
    float* x    = ws;                          // [0,S)
    float* tmp  = ws + 1*S;                    // [S,2S)
    float* q    = ws + 2*S;                    // [2S,3S)
    float* k    = ws + 3*S;                    // [3S,4S)
    float* v    = ws + 4*S;                    // [4S,5S)
    float* att  = ws + 5*S;                    // [5S,6S)
    unsigned short* xb   = (unsigned short*)(ws + 6*S);      // S/2 floats
    unsigned short* attb = xb;                 // aliases xb (xb dead by O-proj)
    unsigned short* wlb  = (unsigned short*)(ws + 6*S + S/2);// per-layer weights
    unsigned short* h1b  = (unsigned short*)(ws + 2*S);      // aliases q,k (dead)
    // total ws use: 7*S floats = 117.4 MB

    const int DD  = D_*D_;       // 262144
    const int DF  = D_*FF_;      // 1048576
    unsigned short* wqb = wlb;
    unsigned short* wkb = wlb + 1*DD;
    unsigned short* wvb = wlb + 2*DD;
    unsigned short* wob = wlb + 3*DD;
    unsigned short* w1b = wlb + 4*DD;
    unsigned short* w2b = wlb + 4*DD + DF;

    const dim3 blk(256);
    const dim3 gD (D_/64,  T_/128);            // fp32 embed GEMM grid
    const dim3 gMD(D_/128, T_/128);            // mfma N=512
    const dim3 gMF(FF_/128, T_/128);           // mfma N=2048

    // embed: x = src @ embed_W^T + embed_b (fp32, K=64)
    gemm_bias_kernel<false><<<gD, blk, 0, stream>>>(src, embed_W, embed_b, x, T_, D_, DIN);

    for (int l = 0; l < L_; l++) {
        // cast this layer's weights to bf16
        Cast6Args ca;
        ca.src[0] = Wq + (size_t)l*DD; ca.dst[0] = wqb; ca.n[0] = DD;
        ca.src[1] = Wk + (size_t)l*DD; ca.dst[1] = wkb; ca.n[1] = DD;
        ca.src[2] = Wv + (size_t)l*DD; ca.dst[2] = wvb; ca.n[2] = DD;
        ca.src[3] = Wo + (size_t)l*DD; ca.dst[3] = wob; ca.n[3] = DD;
        ca.src[4] = W1 + (size_t)l*DF; ca.dst[4] = w1b; ca.n[4] = DF;
        ca.src[5] = W2 + (size_t)l*DF; ca.dst[5] = w2b; ca.n[5] = DF;
        cast6_kernel<<<dim3(DF/1024, 6), blk, 0, stream>>>(ca);

        const float* bql = bq + (size_t)l*D_;
        const float* bkl = bk + (size_t)l*D_;
        const float* bvl = bv + (size_t)l*D_;
        const float* bol = bo + (size_t)l*D_;
        const float* b1l = b1 + (size_t)l*FF_;
        const float* b2l = b2 + (size_t)l*D_;

        cast_bf16_kernel<<<T_*D_/1024, blk, 0, stream>>>(x, xb, T_*D_);
        gemm_mfma_kernel<false,false><<<gMD, blk, 0, stream>>>(xb, wqb, bql, q, T_, D_, D_);
        gemm_mfma_kernel<false,false><<<gMD, blk, 0, stream>>>(xb, wkb, bkl, k, T_, D_, D_);
        gemm_mfma_kernel<false,false><<<gMD, blk, 0, stream>>>(xb, wvb, bvl, v, T_, D_, D_);

        attn_kernel<<<dim3(NSEQ/64, B_*H_), blk, 0, stream>>>(q, k, v, kpm, att);

        cast_bf16_kernel<<<T_*D_/1024, blk, 0, stream>>>(att, attb, T_*D_);
        gemm_mfma_kernel<false,false><<<gMD, blk, 0, stream>>>(attb, wob, bol, tmp, T_, D_, D_);
        add_ln_kernel<<<T_, 128, 0, stream>>>(x, tmp, ln1_g + (size_t)l*D_, ln1_b + (size_t)l*D_);

        cast_bf16_kernel<<<T_*D_/1024, blk, 0, stream>>>(x, xb, T_*D_);
        gemm_mfma_kernel<true, true ><<<gMF, blk, 0, stream>>>(xb, w1b, b1l, h1b, T_, FF_, D_);
        gemm_mfma_kernel<false,false><<<gMD, blk, 0, stream>>>(h1b, w2b, b2l, tmp, T_, D_, FF_);
        add_ln_kernel<<<T_, 128, 0, stream>>>(x, tmp, ln2_g + (size_t)l*D_, ln2_b + (size_t)l*D_);
    }

    add_ln_kernel<<<T_, 128, 0, stream>>>(x, nullptr, fin_g, fin_b);
    head_kernel<<<T_/4, 256, 0, stream>>>(x, head_W, head_b, out);
}

// Round 3
// 1391.211 us; speedup vs baseline: 4.5557x; 2.1674x over previous
//
#include <hip/hip_runtime.h>
#include <hip/hip_bf16.h>
#include <math.h>

#define B_   8
#define NSEQ 1024
#define T_   (B_*NSEQ)     // 8192 tokens
#define DIN  64
#define D_   512
#define H_   8
#define HD_  64
#define FF_  2048
#define L_   6
#define C_   5

typedef __attribute__((ext_vector_type(8))) short bf16x8;
typedef __attribute__((ext_vector_type(4))) float f32x4;

__device__ __forceinline__ unsigned short f2bf(float f) {
    __hip_bfloat16 h = __float2bfloat16(f);
    return *reinterpret_cast<unsigned short*>(&h);
}
__device__ __forceinline__ float bf2f(unsigned short u) {
    __hip_bfloat16 h = *reinterpret_cast<__hip_bfloat16*>(&u);
    return __bfloat162float(h);
}

__device__ __forceinline__ void gload_lds16(const void* g, void* l) {
    __builtin_amdgcn_global_load_lds(
        (const __attribute__((address_space(1))) unsigned int*)g,
        (__attribute__((address_space(3))) unsigned int*)l, 16, 0, 0);
}

// ---------------------------------------------------------------------------
// fp32 GEMM (embed only, K=64): C = A @ W^T + bias
// ---------------------------------------------------------------------------
template<bool RELU>
__global__ __launch_bounds__(256, 2)
void gemm_bias_kernel(const float* __restrict__ A, const float* __restrict__ W,
                      const float* __restrict__ bias, float* __restrict__ C,
                      int M, int N, int K)
{
    constexpr int BM = 128, BN = 64, BK = 16;
    __shared__ float As[BK][BM + 4];
    __shared__ float Ws[BK][BN + 4];
    const int tid = threadIdx.x;
    const int bm  = blockIdx.y * BM;
    const int bn  = blockIdx.x * BN;
    const int tm0 = (tid >> 4) * 4;
    const int tn0 = (tid & 15) * 4;

    float acc[8][4];
    #pragma unroll
    for (int i = 0; i < 8; i++)
        #pragma unroll
        for (int j = 0; j < 4; j++) acc[i][j] = 0.f;

    for (int k0 = 0; k0 < K; k0 += BK) {
        #pragma unroll
        for (int i = 0; i < 2; i++) {
            const int f  = tid + i*256;
            const int r  = f >> 2;
            const int kc = (f & 3) << 2;
            const float4 a4 = *(const float4*)(A + (size_t)(bm + r)*K + k0 + kc);
            As[kc+0][r] = a4.x; As[kc+1][r] = a4.y;
            As[kc+2][r] = a4.z; As[kc+3][r] = a4.w;
        }
        {
            const int r  = tid >> 2;
            const int kc = (tid & 3) << 2;
            const float4 w4 = *(const float4*)(W + (size_t)(bn + r)*K + k0 + kc);
            Ws[kc+0][r] = w4.x; Ws[kc+1][r] = w4.y;
            Ws[kc+2][r] = w4.z; Ws[kc+3][r] = w4.w;
        }
        __syncthreads();
        #pragma unroll
        for (int kk = 0; kk < BK; kk++) {
            const float4 a0 = *(const float4*)&As[kk][tm0];
            const float4 a1 = *(const float4*)&As[kk][tm0 + 64];
            const float4 w0 = *(const float4*)&Ws[kk][tn0];
            const float af[8] = {a0.x,a0.y,a0.z,a0.w,a1.x,a1.y,a1.z,a1.w};
            const float wf[4] = {w0.x,w0.y,w0.z,w0.w};
            #pragma unroll
            for (int i = 0; i < 8; i++)
                #pragma unroll
                for (int j = 0; j < 4; j++)
                    acc[i][j] = fmaf(af[i], wf[j], acc[i][j]);
        }
        __syncthreads();
    }

    const float4 b4 = *(const float4*)(bias + bn + tn0);
    const float bsv[4] = {b4.x, b4.y, b4.z, b4.w};
    #pragma unroll
    for (int i = 0; i < 8; i++) {
        const int r = bm + tm0 + (i & 3) + ((i >> 2) << 6);
        float o[4];
        #pragma unroll
        for (int j = 0; j < 4; j++) {
            float t = acc[i][j] + bsv[j];
            if (RELU) t = fmaxf(t, 0.f);
            o[j] = t;
        }
        *(float4*)(C + (size_t)r*N + bn + tn0) = *(const float4*)o;
    }
}

// ---------------------------------------------------------------------------
// bf16 MFMA GEMM: C[M,N](f32 or bf16) = A[M,K]bf16 @ W[N,K]bf16^T + bias(f32)
// 128x128 tile, BK=64, 4 waves (2x2), 16x16x32 MFMA, XOR-swizzled LDS.
// ---------------------------------------------------------------------------
template<bool RELU, bool OUT_BF16>
__global__ __launch_bounds__(256, 2)
void gemm_mfma_kernel(const unsigned short* __restrict__ A,
                      const unsigned short* __restrict__ W,
                      const float* __restrict__ bias,
                      void* __restrict__ Cout,
                      int M, int N, int K)
{
    constexpr int BM = 128, BN = 128, BK = 64;
    __shared__ short As[BM*BK];
    __shared__ short Bs[BN*BK];
    const int tid = threadIdx.x;
    const int l   = tid & 63;
    const int wid = tid >> 6;
    const int wm  = wid >> 1, wn = wid & 1;
    const int bm  = blockIdx.y * BM;
    const int bn  = blockIdx.x * BN;

    const int srow = l >> 3;
    const int scol = ((l & 7) ^ srow) * 8;

    f32x4 acc[4][4];
    const f32x4 z = {0.f, 0.f, 0.f, 0.f};
    #pragma unroll
    for (int m = 0; m < 4; m++)
        #pragma unroll
        for (int n = 0; n < 4; n++) acc[m][n] = z;

    const int nk = K / BK;
    for (int kt = 0; kt < nk; kt++) {
        const int k0 = kt * BK;
        __syncthreads();
        #pragma unroll
        for (int c = 0; c < 4; c++) {
            const int r = wid*32 + c*8 + srow;
            gload_lds16(A + (size_t)(bm + r)*K + k0 + scol, &As[(wid*32 + c*8)*64]);
            gload_lds16(W + (size_t)(bn + r)*K + k0 + scol, &Bs[(wid*32 + c*8)*64]);
        }
        __syncthreads();

        #pragma unroll
        for (int h = 0; h < 2; h++) {
            bf16x8 af[4], bfr[4];
            #pragma unroll
            for (int m = 0; m < 4; m++) {
                const int R  = wm*64 + m*16 + (l & 15);
                const int cb = (h*64 + (l >> 4)*16) ^ ((R & 7) << 4);
                af[m] = *(const bf16x8*)((const char*)As + R*128 + cb);
            }
            #pragma unroll
            for (int n = 0; n < 4; n++) {
                const int Rc = wn*64 + n*16 + (l & 15);
                const int cb = (h*64 + (l >> 4)*16) ^ ((Rc & 7) << 4);
                bfr[n] = *(const bf16x8*)((const char*)Bs + Rc*128 + cb);
            }
            #pragma unroll
            for (int m = 0; m < 4; m++)
                #pragma unroll
                for (int n = 0; n < 4; n++)
                    acc[m][n] = __builtin_amdgcn_mfma_f32_16x16x32_bf16(af[m], bfr[n], acc[m][n], 0, 0, 0);
        }
    }

    #pragma unroll
    for (int n = 0; n < 4; n++) {
        const int col = bn + wn*64 + n*16 + (l & 15);
        const float bv = bias[col];
        #pragma unroll
        for (int m = 0; m < 4; m++) {
            const int row0 = bm + wm*64 + m*16 + ((l >> 4) << 2);
            #pragma unroll
            for (int j = 0; j < 4; j++) {
                float t = acc[m][n][j] + bv;
                if (RELU) t = fmaxf(t, 0.f);
                if (OUT_BF16)
                    ((unsigned short*)Cout)[(size_t)(row0 + j)*N + col] = f2bf(t);
                else
                    ((float*)Cout)[(size_t)(row0 + j)*N + col] = t;
            }
        }
    }
}

// ---------------------------------------------------------------------------
// bf16 MFMA flash attention. Block = 4 waves, 64 q-rows of one (b,h).
// Wave owns 16 q-rows; KV tiles of 64. Q in regs; K gload_lds+XOR-swizzle;
// V reg-staged transposed [d][kv] pitch 72; P via padded LDS pitch 72.
// fp32 online softmax; inputs/outputs bf16.
// ---------------------------------------------------------------------------
__global__ __launch_bounds__(256, 2)
void attn_mfma_kernel(const unsigned short* __restrict__ Q,
                      const unsigned short* __restrict__ Kg,
                      const unsigned short* __restrict__ Vg,
                      const unsigned char* __restrict__ mask,
                      unsigned short* __restrict__ O)
{
    __shared__ short Ks[64*64];      // swizzled, linear rows of 128 B
    __shared__ short Vt[64*72];      // [d][kv], pitch 72 elems (144 B, 16B-aligned)
    __shared__ short Ps[4*16*72];    // per-wave P [16][72]
    const int tid = threadIdx.x;
    const int l   = tid & 63;
    const int w   = tid >> 6;
    const int b   = blockIdx.y >> 3;
    const int h   = blockIdx.y & 7;
    const int q0  = blockIdx.x * 64;
    const size_t tokbase = (size_t)b * NSEQ;

    // Q fragment: row = w*16 + (l&15), k(d) = (l>>4)*8 + j  (+32 for second half)
    const int qr = q0 + w*16 + (l & 15);
    const unsigned short* qp = Q + (tokbase + qr)*D_ + h*HD_ + (l >> 4)*8;
    const bf16x8 aq0 = *(const bf16x8*)qp;
    const bf16x8 aq1 = *(const bf16x8*)(qp + 32);

    f32x4 accO[4];
    const f32x4 z = {0.f,0.f,0.f,0.f};
    #pragma unroll
    for (int n = 0; n < 4; n++) accO[n] = z;
    float mrow[4] = {-INFINITY,-INFINITY,-INFINITY,-INFINITY};
    float lrow[4] = {0.f,0.f,0.f,0.f};

    const int srow = l >> 3;                 // staging row-in-stripe
    const int scol = ((l & 7) ^ srow) * 8;   // pre-swizzled col (elems)
    const unsigned char* mp = mask + (size_t)b*NSEQ;

    for (int kt = 0; kt < NSEQ/64; kt++) {
        const int kv0 = kt * 64;
        __syncthreads();   // prev tile's LDS reads complete

        // K tile: 2 gload_lds issues per wave (8 rows each)
        #pragma unroll
        for (int c = 0; c < 2; c++) {
            const int rowbase = c*32 + w*8;
            gload_lds16(Kg + (tokbase + kv0 + rowbase + srow)*D_ + h*HD_ + scol,
                        &Ks[rowbase*64]);
        }
        // V tile transposed: thread covers kv = l, d = w*16..w*16+15
        {
            const int vkv = l;
            const int vd0 = w*16;
            const unsigned short* vp = Vg + (tokbase + kv0 + vkv)*D_ + h*HD_ + vd0;
            const bf16x8 v8a = *(const bf16x8*)vp;
            const bf16x8 v8b = *(const bf16x8*)(vp + 8);
            #pragma unroll
            for (int j = 0; j < 8; j++) {
                Vt[(vd0 + j)*72 + vkv]     = v8a[j];
                Vt[(vd0 + 8 + j)*72 + vkv] = v8b[j];
            }
        }
        __syncthreads();   // compiler drains vmcnt before barrier

        // QK^T: S[q=(l>>4)*4+reg][kv=n*16+(l&15)]
        f32x4 s4[4];
        #pragma unroll
        for (int n = 0; n < 4; n++) s4[n] = z;
        #pragma unroll
        for (int ks = 0; ks < 2; ks++) {
            const bf16x8 aq = ks ? aq1 : aq0;
            #pragma unroll
            for (int n = 0; n < 4; n++) {
                const int Rc = n*16 + (l & 15);
                const int cb = (ks*64 + (l >> 4)*16) ^ ((Rc & 7) << 4);
                const bf16x8 bk = *(const bf16x8*)((const char*)Ks + Rc*128 + cb);
                s4[n] = __builtin_amdgcn_mfma_f32_16x16x32_bf16(aq, bk, s4[n], 0, 0, 0);
            }
        }

        // scale + mask
        float sv[4][4];
        unsigned char mb[4];
        #pragma unroll
        for (int n = 0; n < 4; n++) mb[n] = mp[kv0 + n*16 + (l & 15)];
        #pragma unroll
        for (int n = 0; n < 4; n++)
            #pragma unroll
            for (int j = 0; j < 4; j++)
                sv[n][j] = mb[n] ? -INFINITY : s4[n][j]*0.125f;

        // online softmax (rows (l>>4)*4+j; reduce across 16-lane group)
        #pragma unroll
        for (int j = 0; j < 4; j++) {
            float tmax = fmaxf(fmaxf(sv[0][j], sv[1][j]), fmaxf(sv[2][j], sv[3][j]));
            #pragma unroll
            for (int off = 1; off < 16; off <<= 1)
                tmax = fmaxf(tmax, __shfl_xor(tmax, off, 16));
            const float mnew  = fmaxf(mrow[j], tmax);
            const float alpha = __expf(mrow[j] - mnew);
            float rs = 0.f;
            unsigned short pb[4];
            #pragma unroll
            for (int n = 0; n < 4; n++) {
                const float p = __expf(sv[n][j] - mnew);
                pb[n] = f2bf(p);
                rs += bf2f(pb[n]);   // l from ROUNDED p: normalization consistent
            }
            #pragma unroll
            for (int off = 1; off < 16; off <<= 1)
                rs += __shfl_xor(rs, off, 16);
            lrow[j] = lrow[j]*alpha + rs;
            mrow[j] = mnew;
            #pragma unroll
            for (int n = 0; n < 4; n++) accO[n][j] *= alpha;
            const int prow = (l >> 4)*4 + j;
            #pragma unroll
            for (int n = 0; n < 4; n++)
                Ps[w*16*72 + prow*72 + n*16 + (l & 15)] = (short)pb[n];
        }

        // PV: O[q][d=n*16+(l&15)] += P[q][kv] V[kv][d]
        #pragma unroll
        for (int ks = 0; ks < 2; ks++) {
            const bf16x8 ap = *(const bf16x8*)&Ps[w*16*72 + (l & 15)*72 + ks*32 + (l >> 4)*8];
            #pragma unroll
            for (int n = 0; n < 4; n++) {
                const bf16x8 bv = *(const bf16x8*)&Vt[(n*16 + (l & 15))*72 + ks*32 + (l >> 4)*8];
                accO[n] = __builtin_amdgcn_mfma_f32_16x16x32_bf16(ap, bv, accO[n], 0, 0, 0);
            }
        }
    }

    // epilogue: normalize, cast bf16, store
    #pragma unroll
    for (int j = 0; j < 4; j++) {
        const float inv = 1.0f / lrow[j];
        const int row = q0 + w*16 + (l >> 4)*4 + j;
        unsigned short* op = O + (tokbase + row)*D_ + h*HD_;
        #pragma unroll
        for (int n = 0; n < 4; n++)
            op[n*16 + (l & 15)] = f2bf(accO[n][j] * inv);
    }
}

// ---------------------------------------------------------------------------
// Fused (x += delta); LayerNorm; optional bf16 copy out.
// ---------------------------------------------------------------------------
__global__ __launch_bounds__(128)
void add_ln_kernel(float* __restrict__ x, const float* __restrict__ delta,
                   const float* __restrict__ g, const float* __restrict__ bta,
                   unsigned short* __restrict__ xb_out)
{
    const int row = blockIdx.x;
    const int tid = threadIdx.x;
    float* xr = x + (size_t)row*D_;
    float4 xv = *(const float4*)(xr + tid*4);
    if (delta) {
        const float4 dv = *(const float4*)(delta + (size_t)row*D_ + tid*4);
        xv.x += dv.x; xv.y += dv.y; xv.z += dv.z; xv.w += dv.w;
    }
    float sum = xv.x + xv.y + xv.z + xv.w;
    float sq  = xv.x*xv.x + xv.y*xv.y + xv.z*xv.z + xv.w*xv.w;
    #pragma unroll
    for (int off = 1; off < 64; off <<= 1) {
        sum += __shfl_xor(sum, off, 64);
        sq  += __shfl_xor(sq,  off, 64);
    }
    __shared__ float red[2][2];
    if ((tid & 63) == 0) { red[tid >> 6][0] = sum; red[tid >> 6][1] = sq; }
    __syncthreads();
    sum = red[0][0] + red[1][0];
    sq  = red[0][1] + red[1][1];
    const float mu  = sum * (1.f/D_);
    const float var = sq * (1.f/D_) - mu*mu;
    const float rs  = rsqrtf(var + 1e-5f);
    const float4 gv = *(const float4*)(g   + tid*4);
    const float4 bv = *(const float4*)(bta + tid*4);
    float4 o;
    o.x = (xv.x - mu)*rs*gv.x + bv.x;
    o.y = (xv.y - mu)*rs*gv.y + bv.y;
    o.z = (xv.z - mu)*rs*gv.z + bv.z;
    o.w = (xv.w - mu)*rs*gv.w + bv.w;
    *(float4*)(xr + tid*4) = o;
    if (xb_out) {
        ushort4 u;
        u.x = f2bf(o.x); u.y = f2bf(o.y); u.z = f2bf(o.z); u.w = f2bf(o.w);
        *(ushort4*)(xb_out + (size_t)row*D_ + tid*4) = u;
    }
}

// ---------------------------------------------------------------------------
// Head: logits[T,5] = x[T,512] @ head_W[5,512]^T + head_b
// ---------------------------------------------------------------------------
__global__ __launch_bounds__(256)
void head_kernel(const float* __restrict__ x, const float* __restrict__ hw,
                 const float* __restrict__ hb, float* __restrict__ out)
{
    const int lane = threadIdx.x & 63;
    const int row  = blockIdx.x*4 + (threadIdx.x >> 6);
    const float* xr = x + (size_t)row*D_;
    float acc[C_] = {0.f,0.f,0.f,0.f,0.f};
    #pragma unroll
    for (int it = 0; it < D_/64; it++) {
        const int k0 = lane + it*64;
        const float xv = xr[k0];
        #pragma unroll
        for (int c = 0; c < C_; c++) acc[c] = fmaf(xv, hw[c*D_ + k0], acc[c]);
    }
    #pragma unroll
    for (int c = 0; c < C_; c++)
        #pragma unroll
        for (int off = 32; off; off >>= 1)
            acc[c] += __shfl_down(acc[c], off, 64);
    if (lane == 0) {
        #pragma unroll
        for (int c = 0; c < C_; c++) out[(size_t)row*C_ + c] = acc[c] + hb[c];
    }
}

// ---------------------------------------------------------------------------
__global__ __launch_bounds__(256)
void cast_bf16_kernel(const float* __restrict__ in, unsigned short* __restrict__ out, int n)
{
    const int i = (blockIdx.x*256 + threadIdx.x)*4;
    if (i < n) {
        const float4 v = *(const float4*)(in + i);
        ushort4 o;
        o.x = f2bf(v.x); o.y = f2bf(v.y); o.z = f2bf(v.z); o.w = f2bf(v.w);
        *(ushort4*)(out + i) = o;
    }
}

// ---------------------------------------------------------------------------
extern "C" void kernel_launch(void* const* d_in, const int* in_sizes, int n_in,
                              void* d_out, int out_size, void* d_ws, size_t ws_size,
                              hipStream_t stream)
{
    const float* src     = (const float*)d_in[0];
    const unsigned char* kpm = (const unsigned char*)d_in[1];
    const float* embed_W = (const float*)d_in[2];
    const float* embed_b = (const float*)d_in[3];
    const float* Wq = (const float*)d_in[4];
    const float* bq = (const float*)d_in[5];
    const float* Wk = (const float*)d_in[6];
    const float* bk = (const float*)d_in[7];
    const float* Wv = (const float*)d_in[8];
    const float* bv = (const float*)d_in[9];
    const float* Wo = (const float*)d_in[10];
    const float* bo = (const float*)d_in[11];
    const float* W1 = (const float*)d_in[12];
    const float* b1 = (const float*)d_in[13];
    const float* W2 = (const float*)d_in[14];
    const float* b2 = (const float*)d_in[15];
    const float* ln1_g = (const float*)d_in[16];
    const float* ln1_b = (const float*)d_in[17];
    const float* ln2_g = (const float*)d_in[18];
    const float* ln2_b = (const float*)d_in[19];
    const float* fin_g = (const float*)d_in[20];
    const float* fin_b = (const float*)d_in[21];
    const float* head_W = (const float*)d_in[22];
    const float* head_b = (const float*)d_in[23];
    float* out = (float*)d_out;

    float* ws = (float*)d_ws;
    const size_t S = (size_t)T_ * D_;             // 4,194,304
    float* x   = ws;                               // [0,S) f32
    float* tmp = ws + S;                           // [S,2S) f32
    unsigned short* u16 = (unsigned short*)(ws + 2*S);
    unsigned short* xb   = u16;                    // S bf16 elems
    unsigned short* qb   = u16 + 1*S;
    unsigned short* kb   = u16 + 2*S;
    unsigned short* vb   = u16 + 3*S;
    unsigned short* attb = u16 + 4*S;
    unsigned short* h1b  = qb;                     // T_*FF_ = 4S elems, aliases qb..attb (dead)
    unsigned short* wb   = u16 + 5*S;              // weights: 18.87M elems
    const int DD = D_*D_;
    const int DF = D_*FF_;
    unsigned short* wqb = wb;
    unsigned short* wkb = wb + 6*(size_t)DD;
    unsigned short* wvb = wb + 12*(size_t)DD;
    unsigned short* wob = wb + 18*(size_t)DD;
    unsigned short* w1b = wb + 24*(size_t)DD;
    unsigned short* w2b = wb + 24*(size_t)DD + 6*(size_t)DF;
    // total ws: 2S f32 + (5S + 18.87M) bf16 ≈ 113 MB

    const dim3 blk(256);
    const dim3 gE (D_/64,  T_/128);                // fp32 embed grid
    const dim3 gMD(D_/128, T_/128);                // mfma N=512
    const dim3 gMF(FF_/128, T_/128);               // mfma N=2048

    // one-time weight casts (full [L,...] tensors are contiguous)
    cast_bf16_kernel<<<6*DD/1024, blk, 0, stream>>>(Wq, wqb, 6*DD);
    cast_bf16_kernel<<<6*DD/1024, blk, 0, stream>>>(Wk, wkb, 6*DD);
    cast_bf16_kernel<<<6*DD/1024, blk, 0, stream>>>(Wv, wvb, 6*DD);
    cast_bf16_kernel<<<6*DD/1024, blk, 0, stream>>>(Wo, wob, 6*DD);
    cast_bf16_kernel<<<6*DF/1024, blk, 0, stream>>>(W1, w1b, 6*DF);
    cast_bf16_kernel<<<6*DF/1024, blk, 0, stream>>>(W2, w2b, 6*DF);

    // embed: x = src @ embed_W^T + embed_b (fp32), then bf16 copy
    gemm_bias_kernel<false><<<gE, blk, 0, stream>>>(src, embed_W, embed_b, x, T_, D_, DIN);
    cast_bf16_kernel<<<T_*D_/1024, blk, 0, stream>>>(x, xb, T_*D_);

    for (int l = 0; l < L_; l++) {
        const float* bql = bq + (size_t)l*D_;
        const float* bkl = bk + (size_t)l*D_;
        const float* bvl = bv + (size_t)l*D_;
        const float* bol = bo + (size_t)l*D_;
        const float* b1l = b1 + (size_t)l*FF_;
        const float* b2l = b2 + (size_t)l*D_;

        gemm_mfma_kernel<false,true ><<<gMD, blk, 0, stream>>>(xb, wqb + (size_t)l*DD, bql, qb, T_, D_, D_);
        gemm_mfma_kernel<false,true ><<<gMD, blk, 0, stream>>>(xb, wkb + (size_t)l*DD, bkl, kb, T_, D_, D_);
        gemm_mfma_kernel<false,true ><<<gMD, blk, 0, stream>>>(xb, wvb + (size_t)l*DD, bvl, vb, T_, D_, D_);

        attn_mfma_kernel<<<dim3(NSEQ/64, B_*H_), blk, 0, stream>>>(qb, kb, vb, kpm, attb);

        gemm_mfma_kernel<false,false><<<gMD, blk, 0, stream>>>(attb, wob + (size_t)l*DD, bol, tmp, T_, D_, D_);
        add_ln_kernel<<<T_, 128, 0, stream>>>(x, tmp, ln1_g + (size_t)l*D_, ln1_b + (size_t)l*D_, xb);

        gemm_mfma_kernel<true, true ><<<gMF, blk, 0, stream>>>(xb, w1b + (size_t)l*DF, b1l, h1b, T_, FF_, D_);
        gemm_mfma_kernel<false,false><<<gMD, blk, 0, stream>>>(h1b, w2b + (size_t)l*DF, b2l, tmp, T_, D_, FF_);
        add_ln_kernel<<<T_, 128, 0, stream>>>(x, tmp, ln2_g + (size_t)l*D_, ln2_b + (size_t)l*D_, xb);
    }

    add_ln_kernel<<<T_, 128, 0, stream>>>(x, nullptr, fin_g, fin_b, nullptr);
    head_kernel<<<T_/4, 256, 0, stream>>>(x, head_W, head_b, out);
}

// Round 5
// 1281.020 us; speedup vs baseline: 4.9475x; 1.0860x over previous
//
#include <hip/hip_runtime.h>
#include <hip/hip_bf16.h>
#include <math.h>

#define B_   8
#define NSEQ 1024
#define T_   (B_*NSEQ)     // 8192 tokens
#define DIN  64
#define D_   512
#define H_   8
#define HD_  64
#define FF_  2048
#define L_   6
#define C_   5

typedef __attribute__((ext_vector_type(8))) short bf16x8;
typedef __attribute__((ext_vector_type(4))) float f32x4;

__device__ __forceinline__ unsigned short f2bf(float f) {
    __hip_bfloat16 h = __float2bfloat16(f);
    return *reinterpret_cast<unsigned short*>(&h);
}
__device__ __forceinline__ float bf2f(unsigned short u) {
    __hip_bfloat16 h = *reinterpret_cast<__hip_bfloat16*>(&u);
    return __bfloat162float(h);
}

__device__ __forceinline__ void gload_lds16(const void* g, void* l) {
    __builtin_amdgcn_global_load_lds(
        (const __attribute__((address_space(1))) unsigned int*)g,
        (__attribute__((address_space(3))) unsigned int*)l, 16, 0, 0);
}

// ---------------------------------------------------------------------------
// fp32 GEMM (embed only, K=64): C = A @ W^T + bias
// ---------------------------------------------------------------------------
template<bool RELU>
__global__ __launch_bounds__(256, 2)
void gemm_bias_kernel(const float* __restrict__ A, const float* __restrict__ W,
                      const float* __restrict__ bias, float* __restrict__ C,
                      int M, int N, int K)
{
    constexpr int BM = 128, BN = 64, BK = 16;
    __shared__ float As[BK][BM + 4];
    __shared__ float Ws[BK][BN + 4];
    const int tid = threadIdx.x;
    const int bm  = blockIdx.y * BM;
    const int bn  = blockIdx.x * BN;
    const int tm0 = (tid >> 4) * 4;
    const int tn0 = (tid & 15) * 4;

    float acc[8][4];
    #pragma unroll
    for (int i = 0; i < 8; i++)
        #pragma unroll
        for (int j = 0; j < 4; j++) acc[i][j] = 0.f;

    for (int k0 = 0; k0 < K; k0 += BK) {
        #pragma unroll
        for (int i = 0; i < 2; i++) {
            const int f  = tid + i*256;
            const int r  = f >> 2;
            const int kc = (f & 3) << 2;
            const float4 a4 = *(const float4*)(A + (size_t)(bm + r)*K + k0 + kc);
            As[kc+0][r] = a4.x; As[kc+1][r] = a4.y;
            As[kc+2][r] = a4.z; As[kc+3][r] = a4.w;
        }
        {
            const int r  = tid >> 2;
            const int kc = (tid & 3) << 2;
            const float4 w4 = *(const float4*)(W + (size_t)(bn + r)*K + k0 + kc);
            Ws[kc+0][r] = w4.x; Ws[kc+1][r] = w4.y;
            Ws[kc+2][r] = w4.z; Ws[kc+3][r] = w4.w;
        }
        __syncthreads();
        #pragma unroll
        for (int kk = 0; kk < BK; kk++) {
            const float4 a0 = *(const float4*)&As[kk][tm0];
            const float4 a1 = *(const float4*)&As[kk][tm0 + 64];
            const float4 w0 = *(const float4*)&Ws[kk][tn0];
            const float af[8] = {a0.x,a0.y,a0.z,a0.w,a1.x,a1.y,a1.z,a1.w};
            const float wf[4] = {w0.x,w0.y,w0.z,w0.w};
            #pragma unroll
            for (int i = 0; i < 8; i++)
                #pragma unroll
                for (int j = 0; j < 4; j++)
                    acc[i][j] = fmaf(af[i], wf[j], acc[i][j]);
        }
        __syncthreads();
    }

    const float4 b4 = *(const float4*)(bias + bn + tn0);
    const float bsv[4] = {b4.x, b4.y, b4.z, b4.w};
    #pragma unroll
    for (int i = 0; i < 8; i++) {
        const int r = bm + tm0 + (i & 3) + ((i >> 2) << 6);
        float o[4];
        #pragma unroll
        for (int j = 0; j < 4; j++) {
            float t = acc[i][j] + bsv[j];
            if (RELU) t = fmaxf(t, 0.f);
            o[j] = t;
        }
        *(float4*)(C + (size_t)r*N + bn + tn0) = *(const float4*)o;
    }
}

// ---------------------------------------------------------------------------
// bf16 MFMA GEMM: C[M,N](f32 or bf16) = A[M,K]bf16 @ W[N,K]bf16^T + bias(f32)
// 128x128 tile, BK=64, 4 waves (2x2), 16x16x32 MFMA, XOR-swizzled LDS.
// ---------------------------------------------------------------------------
template<bool RELU, bool OUT_BF16>
__global__ __launch_bounds__(256, 2)
void gemm_mfma_kernel(const unsigned short* __restrict__ A,
                      const unsigned short* __restrict__ W,
                      const float* __restrict__ bias,
                      void* __restrict__ Cout,
                      int M, int N, int K)
{
    constexpr int BM = 128, BN = 128, BK = 64;
    __shared__ short As[BM*BK];
    __shared__ short Bs[BN*BK];
    const int tid = threadIdx.x;
    const int l   = tid & 63;
    const int wid = tid >> 6;
    const int wm  = wid >> 1, wn = wid & 1;
    const int bm  = blockIdx.y * BM;
    const int bn  = blockIdx.x * BN;

    const int srow = l >> 3;
    const int scol = ((l & 7) ^ srow) * 8;

    f32x4 acc[4][4];
    const f32x4 z = {0.f, 0.f, 0.f, 0.f};
    #pragma unroll
    for (int m = 0; m < 4; m++)
        #pragma unroll
        for (int n = 0; n < 4; n++) acc[m][n] = z;

    const int nk = K / BK;
    for (int kt = 0; kt < nk; kt++) {
        const int k0 = kt * BK;
        __syncthreads();
        #pragma unroll
        for (int c = 0; c < 4; c++) {
            const int r = wid*32 + c*8 + srow;
            gload_lds16(A + (size_t)(bm + r)*K + k0 + scol, &As[(wid*32 + c*8)*64]);
            gload_lds16(W + (size_t)(bn + r)*K + k0 + scol, &Bs[(wid*32 + c*8)*64]);
        }
        __syncthreads();

        #pragma unroll
        for (int h = 0; h < 2; h++) {
            bf16x8 af[4], bfr[4];
            #pragma unroll
            for (int m = 0; m < 4; m++) {
                const int R  = wm*64 + m*16 + (l & 15);
                const int cb = (h*64 + (l >> 4)*16) ^ ((R & 7) << 4);
                af[m] = *(const bf16x8*)((const char*)As + R*128 + cb);
            }
            #pragma unroll
            for (int n = 0; n < 4; n++) {
                const int Rc = wn*64 + n*16 + (l & 15);
                const int cb = (h*64 + (l >> 4)*16) ^ ((Rc & 7) << 4);
                bfr[n] = *(const bf16x8*)((const char*)Bs + Rc*128 + cb);
            }
            #pragma unroll
            for (int m = 0; m < 4; m++)
                #pragma unroll
                for (int n = 0; n < 4; n++)
                    acc[m][n] = __builtin_amdgcn_mfma_f32_16x16x32_bf16(af[m], bfr[n], acc[m][n], 0, 0, 0);
        }
    }

    #pragma unroll
    for (int n = 0; n < 4; n++) {
        const int col = bn + wn*64 + n*16 + (l & 15);
        const float bv = bias[col];
        #pragma unroll
        for (int m = 0; m < 4; m++) {
            const int row0 = bm + wm*64 + m*16 + ((l >> 4) << 2);
            #pragma unroll
            for (int j = 0; j < 4; j++) {
                float t = acc[m][n][j] + bv;
                if (RELU) t = fmaxf(t, 0.f);
                if (OUT_BF16)
                    ((unsigned short*)Cout)[(size_t)(row0 + j)*N + col] = f2bf(t);
                else
                    ((float*)Cout)[(size_t)(row0 + j)*N + col] = t;
            }
        }
    }
}

// ---------------------------------------------------------------------------
// bf16 MFMA flash attention v3.
// QKV packed [T][1536] (Q|K|V each 512). 4 waves, 64 q-rows/block, KV tile 64.
// - K double-buffered via global_load_lds (XOR-swizzled), 1 barrier/tile
// - V double-buffered via reg-stage (issue-early after barrier, transpose-
//   store into Vt[d][kv] pitch 72 late) -- r3-verified layout & reads
// - swapped QK^T (mfma(K,Q)): lane owns S[kv=16n+4g+r][q=q16], softmax is
//   in-lane over 16 values + 2 shfl_xor across groups
// ---------------------------------------------------------------------------
__global__ __launch_bounds__(256)
void attn_mfma_kernel(const unsigned short* __restrict__ QKV,
                      const unsigned char* __restrict__ mask,
                      unsigned short* __restrict__ O)
{
    constexpr int QS = 1536;
    __shared__ short Ks[2][64*64];   // K tiles, linear 128B rows, XOR-swizzled
    __shared__ short Vt[2][64*72];   // V transposed [d][kv], pitch 72
    __shared__ short Ps[4][16*72];   // per-wave P [q16][kv], pitch 72
    const int tid = threadIdx.x;
    const int l   = tid & 63;
    const int w   = tid >> 6;
    const int g   = l >> 4;          // lane group 0..3
    const int q16 = l & 15;
    const int b   = blockIdx.y >> 3;
    const int h   = blockIdx.y & 7;
    const int q0  = blockIdx.x * 64;
    const size_t tokbase = (size_t)b * NSEQ;

    // Q fragment (B-operand): col=q16 -> q-row w*16+q16; k(d) = 32ks + g*8 + j
    const unsigned short* qp = QKV + (tokbase + q0 + w*16 + q16)*QS + h*HD_ + g*8;
    const bf16x8 bq0 = *(const bf16x8*)qp;
    const bf16x8 bq1 = *(const bf16x8*)(qp + 32);

    f32x4 accO[4];
    const f32x4 z = {0.f,0.f,0.f,0.f};
    #pragma unroll
    for (int n = 0; n < 4; n++) accO[n] = z;
    float mrow = -INFINITY, lrow = 0.f;   // stats for q-row q16 (replicated over g)

    const int srow = l >> 3;                  // K staging: row within stripe
    const int scol = ((l & 7) ^ srow) * 8;    // K staging: pre-swizzled col
    const unsigned char* mp = mask + (size_t)b*NSEQ;

    // prologue: stage K(0); load+store V(0)
    #pragma unroll
    for (int c = 0; c < 2; c++) {
        const int rb = (w*2 + c)*8;
        gload_lds16(QKV + (tokbase + rb + srow)*QS + D_ + h*HD_ + scol, &Ks[0][rb*64]);
    }
    {
        const unsigned short* vp = QKV + (tokbase + l)*QS + 2*D_ + h*HD_ + w*16;
        const bf16x8 v8a = *(const bf16x8*)vp;
        const bf16x8 v8b = *(const bf16x8*)(vp + 8);
        #pragma unroll
        for (int j = 0; j < 8; j++) {
            Vt[0][(w*16 + j)*72 + l]     = v8a[j];
            Vt[0][(w*16 + 8 + j)*72 + l] = v8b[j];
        }
    }

    for (int t = 0; t < NSEQ/64; t++) {
        const int buf = t & 1;
        const int kv0 = t*64;
        __syncthreads();   // stage(t)+V-writes(t) visible; prev reads of buf^1 done

        // issue stage(t+1): K -> Ks[buf^1] (gload_lds), V -> regs (write late)
        bf16x8 nva, nvb;
        const bool more = (t + 1 < NSEQ/64);
        if (more) {
            const int kvn = kv0 + 64;
            #pragma unroll
            for (int c = 0; c < 2; c++) {
                const int rb = (w*2 + c)*8;
                gload_lds16(QKV + (tokbase + kvn + rb + srow)*QS + D_ + h*HD_ + scol,
                            &Ks[buf^1][rb*64]);
            }
            const unsigned short* vp = QKV + (tokbase + kvn + l)*QS + 2*D_ + h*HD_ + w*16;
            nva = *(const bf16x8*)vp;
            nvb = *(const bf16x8*)(vp + 8);
        }

        // QK^T swapped: s4[n][r] = S[kv=16n+4g+r][q=q16]  (A=K rows, B=Q cols)
        f32x4 s4[4];
        #pragma unroll
        for (int n = 0; n < 4; n++) s4[n] = z;
        #pragma unroll
        for (int ks = 0; ks < 2; ks++) {
            const bf16x8 bq = ks ? bq1 : bq0;
            const int cb = (ks*64 + g*16) ^ ((q16 & 7) << 4);
            #pragma unroll
            for (int n = 0; n < 4; n++) {
                const int R = n*16 + q16;
                const bf16x8 ak = *(const bf16x8*)((const char*)&Ks[buf][0] + R*128 + cb);
                s4[n] = __builtin_amdgcn_mfma_f32_16x16x32_bf16(ak, bq, s4[n], 0, 0, 0);
            }
        }

        float sv[4][4];
        #pragma unroll
        for (int n = 0; n < 4; n++)
            #pragma unroll
            for (int r = 0; r < 4; r++) sv[n][r] = s4[n][r]*0.125f;

        const unsigned long long mbits = __ballot(mp[kv0 + l] != 0);
        if (mbits) {   // wave-uniform; skipped for all-false mask
            #pragma unroll
            for (int n = 0; n < 4; n++)
                #pragma unroll
                for (int r = 0; r < 4; r++)
                    if ((mbits >> (unsigned)(16*n + 4*g + r)) & 1ULL) sv[n][r] = -INFINITY;
        }

        // softmax: in-lane max/sum over 16, combine across 4 groups
        float tmax = sv[0][0];
        #pragma unroll
        for (int n = 0; n < 4; n++)
            #pragma unroll
            for (int r = 0; r < 4; r++) tmax = fmaxf(tmax, sv[n][r]);
        tmax = fmaxf(tmax, __shfl_xor(tmax, 16));
        tmax = fmaxf(tmax, __shfl_xor(tmax, 32));
        const float mnew  = fmaxf(mrow, tmax);
        const float alpha = __expf(mrow - mnew);
        float rs = 0.f;
        unsigned int pw[4][2];
        #pragma unroll
        for (int n = 0; n < 4; n++) {
            const unsigned short p0 = f2bf(__expf(sv[n][0] - mnew));
            const unsigned short p1 = f2bf(__expf(sv[n][1] - mnew));
            const unsigned short p2 = f2bf(__expf(sv[n][2] - mnew));
            const unsigned short p3 = f2bf(__expf(sv[n][3] - mnew));
            pw[n][0] = (unsigned)p0 | ((unsigned)p1 << 16);
            pw[n][1] = (unsigned)p2 | ((unsigned)p3 << 16);
            rs += bf2f(p0) + bf2f(p1) + bf2f(p2) + bf2f(p3);  // sum ROUNDED p
        }
        rs += __shfl_xor(rs, 16);
        rs += __shfl_xor(rs, 32);
        lrow = lrow*alpha + rs;
        mrow = mnew;

        // rescale accO rows q'=4g+r by alpha(q')
        float alr[4];
        #pragma unroll
        for (int r = 0; r < 4; r++) alr[r] = __shfl(alpha, g*4 + r, 16);
        #pragma unroll
        for (int n = 0; n < 4; n++)
            #pragma unroll
            for (int r = 0; r < 4; r++) accO[n][r] *= alr[r];

        // P -> LDS: row q16, kv slots 16n+4g..+3 (ds_write_b64 x4)
        #pragma unroll
        for (int n = 0; n < 4; n++) {
            uint2 u; u.x = pw[n][0]; u.y = pw[n][1];
            *(uint2*)&Ps[w][q16*72 + 16*n + 4*g] = u;
        }

        // PV: accO[n][r] for q'=4g+r, d=16n+q16  (A=P rows q, B=V cols d)
        #pragma unroll
        for (int ks = 0; ks < 2; ks++) {
            const bf16x8 ap = *(const bf16x8*)&Ps[w][q16*72 + ks*32 + g*8];
            #pragma unroll
            for (int n = 0; n < 4; n++) {
                const bf16x8 bv = *(const bf16x8*)&Vt[buf][(n*16 + q16)*72 + ks*32 + g*8];
                accO[n] = __builtin_amdgcn_mfma_f32_16x16x32_bf16(ap, bv, accO[n], 0, 0, 0);
            }
        }

        // write V(t+1) into Vt[buf^1] (its last readers finished before barrier)
        if (more) {
            #pragma unroll
            for (int j = 0; j < 8; j++) {
                Vt[buf^1][(w*16 + j)*72 + l]     = nva[j];
                Vt[buf^1][(w*16 + 8 + j)*72 + l] = nvb[j];
            }
        }
    }

    // epilogue: normalize rows q'=4g+r, store bf16
    float linv[4];
    #pragma unroll
    for (int r = 0; r < 4; r++) linv[r] = 1.0f / __shfl(lrow, g*4 + r, 16);
    #pragma unroll
    for (int r = 0; r < 4; r++) {
        unsigned short* op = O + (tokbase + q0 + w*16 + 4*g + r)*D_ + h*HD_;
        #pragma unroll
        for (int n = 0; n < 4; n++)
            op[16*n + q16] = f2bf(accO[n][r] * linv[r]);
    }
}

// ---------------------------------------------------------------------------
// Fused (x += delta); LayerNorm; optional bf16 copy out.
// ---------------------------------------------------------------------------
__global__ __launch_bounds__(128)
void add_ln_kernel(float* __restrict__ x, const float* __restrict__ delta,
                   const float* __restrict__ g, const float* __restrict__ bta,
                   unsigned short* __restrict__ xb_out)
{
    const int row = blockIdx.x;
    const int tid = threadIdx.x;
    float* xr = x + (size_t)row*D_;
    float4 xv = *(const float4*)(xr + tid*4);
    if (delta) {
        const float4 dv = *(const float4*)(delta + (size_t)row*D_ + tid*4);
        xv.x += dv.x; xv.y += dv.y; xv.z += dv.z; xv.w += dv.w;
    }
    float sum = xv.x + xv.y + xv.z + xv.w;
    float sq  = xv.x*xv.x + xv.y*xv.y + xv.z*xv.z + xv.w*xv.w;
    #pragma unroll
    for (int off = 1; off < 64; off <<= 1) {
        sum += __shfl_xor(sum, off, 64);
        sq  += __shfl_xor(sq,  off, 64);
    }
    __shared__ float red[2][2];
    if ((tid & 63) == 0) { red[tid >> 6][0] = sum; red[tid >> 6][1] = sq; }
    __syncthreads();
    sum = red[0][0] + red[1][0];
    sq  = red[0][1] + red[1][1];
    const float mu  = sum * (1.f/D_);
    const float var = sq * (1.f/D_) - mu*mu;
    const float rs  = rsqrtf(var + 1e-5f);
    const float4 gv = *(const float4*)(g   + tid*4);
    const float4 bv = *(const float4*)(bta + tid*4);
    float4 o;
    o.x = (xv.x - mu)*rs*gv.x + bv.x;
    o.y = (xv.y - mu)*rs*gv.y + bv.y;
    o.z = (xv.z - mu)*rs*gv.z + bv.z;
    o.w = (xv.w - mu)*rs*gv.w + bv.w;
    *(float4*)(xr + tid*4) = o;
    if (xb_out) {
        ushort4 u;
        u.x = f2bf(o.x); u.y = f2bf(o.y); u.z = f2bf(o.z); u.w = f2bf(o.w);
        *(ushort4*)(xb_out + (size_t)row*D_ + tid*4) = u;
    }
}

// ---------------------------------------------------------------------------
// Head: logits[T,5] = x[T,512] @ head_W[5,512]^T + head_b
// ---------------------------------------------------------------------------
__global__ __launch_bounds__(256)
void head_kernel(const float* __restrict__ x, const float* __restrict__ hw,
                 const float* __restrict__ hb, float* __restrict__ out)
{
    const int lane = threadIdx.x & 63;
    const int row  = blockIdx.x*4 + (threadIdx.x >> 6);
    const float* xr = x + (size_t)row*D_;
    float acc[C_] = {0.f,0.f,0.f,0.f,0.f};
    #pragma unroll
    for (int it = 0; it < D_/64; it++) {
        const int k0 = lane + it*64;
        const float xv = xr[k0];
        #pragma unroll
        for (int c = 0; c < C_; c++) acc[c] = fmaf(xv, hw[c*D_ + k0], acc[c]);
    }
    #pragma unroll
    for (int c = 0; c < C_; c++)
        #pragma unroll
        for (int off = 32; off; off >>= 1)
            acc[c] += __shfl_down(acc[c], off, 64);
    if (lane == 0) {
        #pragma unroll
        for (int c = 0; c < C_; c++) out[(size_t)row*C_ + c] = acc[c] + hb[c];
    }
}

// ---------------------------------------------------------------------------
__global__ __launch_bounds__(256)
void cast_bf16_kernel(const float* __restrict__ in, unsigned short* __restrict__ out, int n)
{
    const int i = (blockIdx.x*256 + threadIdx.x)*4;
    if (i < n) {
        const float4 v = *(const float4*)(in + i);
        ushort4 o;
        o.x = f2bf(v.x); o.y = f2bf(v.y); o.z = f2bf(v.z); o.w = f2bf(v.w);
        *(ushort4*)(out + i) = o;
    }
}

// cast Wq/Wk/Wv into packed [L][1536][512] bf16
__global__ __launch_bounds__(256)
void cast_qkv_kernel(const float* __restrict__ Wq, const float* __restrict__ Wk,
                     const float* __restrict__ Wv, unsigned short* __restrict__ dst)
{
    const int t  = blockIdx.y;          // 0..17
    const int ll = t / 3, wh = t % 3;
    const int DD = D_*D_;
    const float* srcs[3] = {Wq, Wk, Wv};
    const float* src = srcs[wh] + (size_t)ll*DD;
    unsigned short* d = dst + (size_t)ll*3*DD + (size_t)wh*DD;
    const int i = (blockIdx.x*256 + threadIdx.x)*4;
    if (i < DD) {
        const float4 v = *(const float4*)(src + i);
        ushort4 o;
        o.x = f2bf(v.x); o.y = f2bf(v.y); o.z = f2bf(v.z); o.w = f2bf(v.w);
        *(ushort4*)(d + i) = o;
    }
}

// concat per-layer qkv bias: [L][1536] f32
__global__ __launch_bounds__(256)
void qkv_bias_kernel(const float* __restrict__ bq, const float* __restrict__ bk,
                     const float* __restrict__ bv, float* __restrict__ dst)
{
    const int idx = blockIdx.x*256 + threadIdx.x;   // < 6*1536
    const int ll = idx / 1536, c = idx % 1536;
    float v;
    if (c < 512)       v = bq[ll*512 + c];
    else if (c < 1024) v = bk[ll*512 + c - 512];
    else               v = bv[ll*512 + c - 1024];
    dst[idx] = v;
}

// ---------------------------------------------------------------------------
extern "C" void kernel_launch(void* const* d_in, const int* in_sizes, int n_in,
                              void* d_out, int out_size, void* d_ws, size_t ws_size,
                              hipStream_t stream)
{
    const float* src     = (const float*)d_in[0];
    const unsigned char* kpm = (const unsigned char*)d_in[1];
    const float* embed_W = (const float*)d_in[2];
    const float* embed_b = (const float*)d_in[3];
    const float* Wq = (const float*)d_in[4];
    const float* bq = (const float*)d_in[5];
    const float* Wk = (const float*)d_in[6];
    const float* bk = (const float*)d_in[7];
    const float* Wv = (const float*)d_in[8];
    const float* bv = (const float*)d_in[9];
    const float* Wo = (const float*)d_in[10];
    const float* bo = (const float*)d_in[11];
    const float* W1 = (const float*)d_in[12];
    const float* b1 = (const float*)d_in[13];
    const float* W2 = (const float*)d_in[14];
    const float* b2 = (const float*)d_in[15];
    const float* ln1_g = (const float*)d_in[16];
    const float* ln1_b = (const float*)d_in[17];
    const float* ln2_g = (const float*)d_in[18];
    const float* ln2_b = (const float*)d_in[19];
    const float* fin_g = (const float*)d_in[20];
    const float* fin_b = (const float*)d_in[21];
    const float* head_W = (const float*)d_in[22];
    const float* head_b = (const float*)d_in[23];
    float* out = (float*)d_out;

    float* ws = (float*)d_ws;
    const size_t S = (size_t)T_ * D_;             // 4,194,304
    float* x   = ws;                               // [0,S) f32
    float* tmp = ws + S;                           // [S,2S) f32
    unsigned short* u16  = (unsigned short*)(ws + 2*S);
    unsigned short* xb   = u16;                    // S elems
    unsigned short* qkvb = u16 + 1*S;              // 3S elems: [T][1536]
    unsigned short* attb = u16 + 4*S;              // S elems
    unsigned short* h1b  = u16 + 1*S;              // 4S elems, aliases qkvb+attb (dead)
    unsigned short* wb   = u16 + 5*S;
    const int DD = D_*D_;
    const int DF = D_*FF_;
    unsigned short* wqkvb = wb;                    // 18*DD
    unsigned short* wob   = wb + 18*(size_t)DD;    // 6*DD
    unsigned short* w1b   = wb + 24*(size_t)DD;    // 24*DD
    unsigned short* w2b   = wb + 48*(size_t)DD;    // 24*DD
    float* qkvbias        = (float*)(wb + 72*(size_t)DD);  // 6*1536 f32

    const dim3 blk(256);
    const dim3 gE  (D_/64,   T_/128);              // fp32 embed grid
    const dim3 gQKV(1536/128, T_/128);             // fused qkv: 12 x 64
    const dim3 gMD (D_/128,  T_/128);              // N=512
    const dim3 gMF (FF_/128, T_/128);              // N=2048

    // one-time weight prep
    cast_qkv_kernel<<<dim3(DD/1024, 18), blk, 0, stream>>>(Wq, Wk, Wv, wqkvb);
    cast_bf16_kernel<<<6*DD/1024, blk, 0, stream>>>(Wo, wob, 6*DD);
    cast_bf16_kernel<<<6*DF/1024, blk, 0, stream>>>(W1, w1b, 6*DF);
    cast_bf16_kernel<<<6*DF/1024, blk, 0, stream>>>(W2, w2b, 6*DF);
    qkv_bias_kernel<<<(6*1536)/256, blk, 0, stream>>>(bq, bk, bv, qkvbias);

    // embed (fp32) + bf16 copy
    gemm_bias_kernel<false><<<gE, blk, 0, stream>>>(src, embed_W, embed_b, x, T_, D_, DIN);
    cast_bf16_kernel<<<T_*D_/1024, blk, 0, stream>>>(x, xb, T_*D_);

    for (int l = 0; l < L_; l++) {
        const float* bol = bo + (size_t)l*D_;
        const float* b1l = b1 + (size_t)l*FF_;
        const float* b2l = b2 + (size_t)l*D_;

        // fused QKV projection -> qkvb [T][1536] bf16
        gemm_mfma_kernel<false,true ><<<gQKV, blk, 0, stream>>>(xb, wqkvb + (size_t)l*3*DD,
                                                                qkvbias + (size_t)l*1536, qkvb, T_, 1536, D_);

        attn_mfma_kernel<<<dim3(NSEQ/64, B_*H_), blk, 0, stream>>>(qkvb, kpm, attb);

        gemm_mfma_kernel<false,false><<<gMD, blk, 0, stream>>>(attb, wob + (size_t)l*DD, bol, tmp, T_, D_, D_);
        add_ln_kernel<<<T_, 128, 0, stream>>>(x, tmp, ln1_g + (size_t)l*D_, ln1_b + (size_t)l*D_, xb);

        gemm_mfma_kernel<true, true ><<<gMF, blk, 0, stream>>>(xb, w1b + (size_t)l*DF, b1l, h1b, T_, FF_, D_);
        gemm_mfma_kernel<false,false><<<gMD, blk, 0, stream>>>(h1b, w2b + (size_t)l*DF, b2l, tmp, T_, D_, FF_);
        add_ln_kernel<<<T_, 128, 0, stream>>>(x, tmp, ln2_g + (size_t)l*D_, ln2_b + (size_t)l*D_, xb);
    }

    add_ln_kernel<<<T_, 128, 0, stream>>>(x, nullptr, fin_g, fin_b, nullptr);
    head_kernel<<<T_/4, 256, 0, stream>>>(x, head_W, head_b, out);
}

// Round 7
// 1272.293 us; speedup vs baseline: 4.9815x; 1.0069x over previous
//
#include <hip/hip_runtime.h>
#include <hip/hip_bf16.h>
#include <math.h>

#define B_   8
#define NSEQ 1024
#define T_   (B_*NSEQ)     // 8192 tokens
#define DIN  64
#define D_   512
#define H_   8
#define HD_  64
#define FF_  2048
#define L_   6
#define C_   5

typedef __attribute__((ext_vector_type(8))) short bf16x8;
typedef __attribute__((ext_vector_type(4))) float f32x4;

__device__ __forceinline__ unsigned short f2bf(float f) {
    __hip_bfloat16 h = __float2bfloat16(f);
    return *reinterpret_cast<unsigned short*>(&h);
}
__device__ __forceinline__ float bf2f(unsigned short u) {
    __hip_bfloat16 h = *reinterpret_cast<__hip_bfloat16*>(&u);
    return __bfloat162float(h);
}

__device__ __forceinline__ void gload_lds16(const void* g, void* l) {
    __builtin_amdgcn_global_load_lds(
        (const __attribute__((address_space(1))) unsigned int*)g,
        (__attribute__((address_space(3))) unsigned int*)l, 16, 0, 0);
}

// ---------------------------------------------------------------------------
// fp32 GEMM (embed only, K=64): C = A @ W^T + bias
// ---------------------------------------------------------------------------
template<bool RELU>
__global__ __launch_bounds__(256, 2)
void gemm_bias_kernel(const float* __restrict__ A, const float* __restrict__ W,
                      const float* __restrict__ bias, float* __restrict__ C,
                      int M, int N, int K)
{
    constexpr int BM = 128, BN = 64, BK = 16;
    __shared__ float As[BK][BM + 4];
    __shared__ float Ws[BK][BN + 4];
    const int tid = threadIdx.x;
    const int bm  = blockIdx.y * BM;
    const int bn  = blockIdx.x * BN;
    const int tm0 = (tid >> 4) * 4;
    const int tn0 = (tid & 15) * 4;

    float acc[8][4];
    #pragma unroll
    for (int i = 0; i < 8; i++)
        #pragma unroll
        for (int j = 0; j < 4; j++) acc[i][j] = 0.f;

    for (int k0 = 0; k0 < K; k0 += BK) {
        #pragma unroll
        for (int i = 0; i < 2; i++) {
            const int f  = tid + i*256;
            const int r  = f >> 2;
            const int kc = (f & 3) << 2;
            const float4 a4 = *(const float4*)(A + (size_t)(bm + r)*K + k0 + kc);
            As[kc+0][r] = a4.x; As[kc+1][r] = a4.y;
            As[kc+2][r] = a4.z; As[kc+3][r] = a4.w;
        }
        {
            const int r  = tid >> 2;
            const int kc = (tid & 3) << 2;
            const float4 w4 = *(const float4*)(W + (size_t)(bn + r)*K + k0 + kc);
            Ws[kc+0][r] = w4.x; Ws[kc+1][r] = w4.y;
            Ws[kc+2][r] = w4.z; Ws[kc+3][r] = w4.w;
        }
        __syncthreads();
        #pragma unroll
        for (int kk = 0; kk < BK; kk++) {
            const float4 a0 = *(const float4*)&As[kk][tm0];
            const float4 a1 = *(const float4*)&As[kk][tm0 + 64];
            const float4 w0 = *(const float4*)&Ws[kk][tn0];
            const float af[8] = {a0.x,a0.y,a0.z,a0.w,a1.x,a1.y,a1.z,a1.w};
            const float wf[4] = {w0.x,w0.y,w0.z,w0.w};
            #pragma unroll
            for (int i = 0; i < 8; i++)
                #pragma unroll
                for (int j = 0; j < 4; j++)
                    acc[i][j] = fmaf(af[i], wf[j], acc[i][j]);
        }
        __syncthreads();
    }

    const float4 b4 = *(const float4*)(bias + bn + tn0);
    const float bsv[4] = {b4.x, b4.y, b4.z, b4.w};
    #pragma unroll
    for (int i = 0; i < 8; i++) {
        const int r = bm + tm0 + (i & 3) + ((i >> 2) << 6);
        float o[4];
        #pragma unroll
        for (int j = 0; j < 4; j++) {
            float t = acc[i][j] + bsv[j];
            if (RELU) t = fmaxf(t, 0.f);
            o[j] = t;
        }
        *(float4*)(C + (size_t)r*N + bn + tn0) = *(const float4*)o;
    }
}

// ---------------------------------------------------------------------------
// bf16 MFMA GEMM, 2-phase double-buffered: C = A @ W^T + bias.
// BM=128, BK=64, BN template (128 or 64). 4 waves (2x2), 16x16x32 MFMA,
// XOR-swizzled LDS, global_load_lds staging overlapped with compute
// (stage(t+1) issued before compute(t); one barrier per K-step).
// ---------------------------------------------------------------------------
template<bool RELU, bool OUT_BF16, int BN>
__global__ __launch_bounds__(256, BN==64 ? 3 : 2)
void gemm_mfma_kernel(const unsigned short* __restrict__ A,
                      const unsigned short* __restrict__ W,
                      const float* __restrict__ bias,
                      void* __restrict__ Cout,
                      int M, int N, int K)
{
    constexpr int BM = 128, BK = 64;
    constexpr int NFN = BN/32;            // 4 (BN=128) or 2 (BN=64)
    __shared__ short As[2][BM*BK];
    __shared__ short Bs[2][BN*BK];
    const int tid = threadIdx.x;
    const int l   = tid & 63;
    const int wid = tid >> 6;
    const int wm  = wid >> 1, wn = wid & 1;
    const int bm  = blockIdx.y * BM;
    const int bn  = blockIdx.x * BN;

    const int srow = l >> 3;
    const int scol = ((l & 7) ^ srow) * 8;

    f32x4 acc[4][NFN];
    const f32x4 z = {0.f, 0.f, 0.f, 0.f};
    #pragma unroll
    for (int m = 0; m < 4; m++)
        #pragma unroll
        for (int n = 0; n < NFN; n++) acc[m][n] = z;

    const int nk = K / BK;

    auto stage = [&](int kt, int sb) {
        const int k0 = kt * BK;
        #pragma unroll
        for (int c = 0; c < 4; c++) {
            const int r = wid*32 + c*8 + srow;
            gload_lds16(A + (size_t)(bm + r)*K + k0 + scol, &As[sb][(wid*32 + c*8)*64]);
        }
        #pragma unroll
        for (int c = 0; c < BN/32; c++) {
            const int r = wid*(BN/4) + c*8 + srow;
            gload_lds16(W + (size_t)(bn + r)*K + k0 + scol, &Bs[sb][(wid*(BN/4) + c*8)*64]);
        }
    };

    stage(0, 0);
    int buf = 0;
    for (int kt = 0; kt < nk; kt++) {
        __syncthreads();   // compiler drains vmcnt(0): stage(kt) landed (issued last iter)
        if (kt + 1 < nk) stage(kt + 1, buf ^ 1);   // in flight under compute(kt)

        #pragma unroll
        for (int h = 0; h < 2; h++) {
            bf16x8 af[4], bfr[NFN];
            #pragma unroll
            for (int m = 0; m < 4; m++) {
                const int R  = wm*64 + m*16 + (l & 15);
                const int cb = (h*64 + (l >> 4)*16) ^ ((R & 7) << 4);
                af[m] = *(const bf16x8*)((const char*)&As[buf][0] + R*128 + cb);
            }
            #pragma unroll
            for (int n = 0; n < NFN; n++) {
                const int Rc = wn*(BN/2) + n*16 + (l & 15);
                const int cb = (h*64 + (l >> 4)*16) ^ ((Rc & 7) << 4);
                bfr[n] = *(const bf16x8*)((const char*)&Bs[buf][0] + Rc*128 + cb);
            }
            #pragma unroll
            for (int m = 0; m < 4; m++)
                #pragma unroll
                for (int n = 0; n < NFN; n++)
                    acc[m][n] = __builtin_amdgcn_mfma_f32_16x16x32_bf16(af[m], bfr[n], acc[m][n], 0, 0, 0);
        }
        buf ^= 1;
    }

    // C/D layout: col = lane&15, row = (lane>>4)*4 + reg   [m89-verified]
    #pragma unroll
    for (int n = 0; n < NFN; n++) {
        const int col = bn + wn*(BN/2) + n*16 + (l & 15);
        const float bv = bias[col];
        #pragma unroll
        for (int m = 0; m < 4; m++) {
            const int row0 = bm + wm*64 + m*16 + ((l >> 4) << 2);
            #pragma unroll
            for (int j = 0; j < 4; j++) {
                float t = acc[m][n][j] + bv;
                if (RELU) t = fmaxf(t, 0.f);
                if (OUT_BF16)
                    ((unsigned short*)Cout)[(size_t)(row0 + j)*N + col] = f2bf(t);
                else
                    ((float*)Cout)[(size_t)(row0 + j)*N + col] = t;
            }
        }
    }
}

// ---------------------------------------------------------------------------
// bf16 MFMA flash attention v3 (unchanged — passing).
// ---------------------------------------------------------------------------
__global__ __launch_bounds__(256)
void attn_mfma_kernel(const unsigned short* __restrict__ QKV,
                      const unsigned char* __restrict__ mask,
                      unsigned short* __restrict__ O)
{
    constexpr int QS = 1536;
    __shared__ short Ks[2][64*64];   // K tiles, linear 128B rows, XOR-swizzled
    __shared__ short Vt[2][64*72];   // V transposed [d][kv], pitch 72
    __shared__ short Ps[4][16*72];   // per-wave P [q16][kv], pitch 72
    const int tid = threadIdx.x;
    const int l   = tid & 63;
    const int w   = tid >> 6;
    const int g   = l >> 4;          // lane group 0..3
    const int q16 = l & 15;
    const int b   = blockIdx.y >> 3;
    const int h   = blockIdx.y & 7;
    const int q0  = blockIdx.x * 64;
    const size_t tokbase = (size_t)b * NSEQ;

    const unsigned short* qp = QKV + (tokbase + q0 + w*16 + q16)*QS + h*HD_ + g*8;
    const bf16x8 bq0 = *(const bf16x8*)qp;
    const bf16x8 bq1 = *(const bf16x8*)(qp + 32);

    f32x4 accO[4];
    const f32x4 z = {0.f,0.f,0.f,0.f};
    #pragma unroll
    for (int n = 0; n < 4; n++) accO[n] = z;
    float mrow = -INFINITY, lrow = 0.f;

    const int srow = l >> 3;
    const int scol = ((l & 7) ^ srow) * 8;
    const unsigned char* mp = mask + (size_t)b*NSEQ;

    #pragma unroll
    for (int c = 0; c < 2; c++) {
        const int rb = (w*2 + c)*8;
        gload_lds16(QKV + (tokbase + rb + srow)*QS + D_ + h*HD_ + scol, &Ks[0][rb*64]);
    }
    {
        const unsigned short* vp = QKV + (tokbase + l)*QS + 2*D_ + h*HD_ + w*16;
        const bf16x8 v8a = *(const bf16x8*)vp;
        const bf16x8 v8b = *(const bf16x8*)(vp + 8);
        #pragma unroll
        for (int j = 0; j < 8; j++) {
            Vt[0][(w*16 + j)*72 + l]     = v8a[j];
            Vt[0][(w*16 + 8 + j)*72 + l] = v8b[j];
        }
    }

    for (int t = 0; t < NSEQ/64; t++) {
        const int buf = t & 1;
        const int kv0 = t*64;
        __syncthreads();

        bf16x8 nva, nvb;
        const bool more = (t + 1 < NSEQ/64);
        if (more) {
            const int kvn = kv0 + 64;
            #pragma unroll
            for (int c = 0; c < 2; c++) {
                const int rb = (w*2 + c)*8;
                gload_lds16(QKV + (tokbase + kvn + rb + srow)*QS + D_ + h*HD_ + scol,
                            &Ks[buf^1][rb*64]);
            }
            const unsigned short* vp = QKV + (tokbase + kvn + l)*QS + 2*D_ + h*HD_ + w*16;
            nva = *(const bf16x8*)vp;
            nvb = *(const bf16x8*)(vp + 8);
        }

        f32x4 s4[4];
        #pragma unroll
        for (int n = 0; n < 4; n++) s4[n] = z;
        #pragma unroll
        for (int ks = 0; ks < 2; ks++) {
            const bf16x8 bq = ks ? bq1 : bq0;
            const int cb = (ks*64 + g*16) ^ ((q16 & 7) << 4);
            #pragma unroll
            for (int n = 0; n < 4; n++) {
                const int R = n*16 + q16;
                const bf16x8 ak = *(const bf16x8*)((const char*)&Ks[buf][0] + R*128 + cb);
                s4[n] = __builtin_amdgcn_mfma_f32_16x16x32_bf16(ak, bq, s4[n], 0, 0, 0);
            }
        }

        float sv[4][4];
        #pragma unroll
        for (int n = 0; n < 4; n++)
            #pragma unroll
            for (int r = 0; r < 4; r++) sv[n][r] = s4[n][r]*0.125f;

        const unsigned long long mbits = __ballot(mp[kv0 + l] != 0);
        if (mbits) {
            #pragma unroll
            for (int n = 0; n < 4; n++)
                #pragma unroll
                for (int r = 0; r < 4; r++)
                    if ((mbits >> (unsigned)(16*n + 4*g + r)) & 1ULL) sv[n][r] = -INFINITY;
        }

        float tmax = sv[0][0];
        #pragma unroll
        for (int n = 0; n < 4; n++)
            #pragma unroll
            for (int r = 0; r < 4; r++) tmax = fmaxf(tmax, sv[n][r]);
        tmax = fmaxf(tmax, __shfl_xor(tmax, 16));
        tmax = fmaxf(tmax, __shfl_xor(tmax, 32));
        const float mnew  = fmaxf(mrow, tmax);
        const float alpha = __expf(mrow - mnew);
        float rs = 0.f;
        unsigned int pw[4][2];
        #pragma unroll
        for (int n = 0; n < 4; n++) {
            const unsigned short p0 = f2bf(__expf(sv[n][0] - mnew));
            const unsigned short p1 = f2bf(__expf(sv[n][1] - mnew));
            const unsigned short p2 = f2bf(__expf(sv[n][2] - mnew));
            const unsigned short p3 = f2bf(__expf(sv[n][3] - mnew));
            pw[n][0] = (unsigned)p0 | ((unsigned)p1 << 16);
            pw[n][1] = (unsigned)p2 | ((unsigned)p3 << 16);
            rs += bf2f(p0) + bf2f(p1) + bf2f(p2) + bf2f(p3);
        }
        rs += __shfl_xor(rs, 16);
        rs += __shfl_xor(rs, 32);
        lrow = lrow*alpha + rs;
        mrow = mnew;

        float alr[4];
        #pragma unroll
        for (int r = 0; r < 4; r++) alr[r] = __shfl(alpha, g*4 + r, 16);
        #pragma unroll
        for (int n = 0; n < 4; n++)
            #pragma unroll
            for (int r = 0; r < 4; r++) accO[n][r] *= alr[r];

        #pragma unroll
        for (int n = 0; n < 4; n++) {
            uint2 u; u.x = pw[n][0]; u.y = pw[n][1];
            *(uint2*)&Ps[w][q16*72 + 16*n + 4*g] = u;
        }

        #pragma unroll
        for (int ks = 0; ks < 2; ks++) {
            const bf16x8 ap = *(const bf16x8*)&Ps[w][q16*72 + ks*32 + g*8];
            #pragma unroll
            for (int n = 0; n < 4; n++) {
                const bf16x8 bv = *(const bf16x8*)&Vt[buf][(n*16 + q16)*72 + ks*32 + g*8];
                accO[n] = __builtin_amdgcn_mfma_f32_16x16x32_bf16(ap, bv, accO[n], 0, 0, 0);
            }
        }

        if (more) {
            #pragma unroll
            for (int j = 0; j < 8; j++) {
                Vt[buf^1][(w*16 + j)*72 + l]     = nva[j];
                Vt[buf^1][(w*16 + 8 + j)*72 + l] = nvb[j];
            }
        }
    }

    float linv[4];
    #pragma unroll
    for (int r = 0; r < 4; r++) linv[r] = 1.0f / __shfl(lrow, g*4 + r, 16);
    #pragma unroll
    for (int r = 0; r < 4; r++) {
        unsigned short* op = O + (tokbase + q0 + w*16 + 4*g + r)*D_ + h*HD_;
        #pragma unroll
        for (int n = 0; n < 4; n++)
            op[16*n + q16] = f2bf(accO[n][r] * linv[r]);
    }
}

// ---------------------------------------------------------------------------
// Fused (x += delta); LayerNorm; optional bf16 copy out.
// ---------------------------------------------------------------------------
__global__ __launch_bounds__(128)
void add_ln_kernel(float* __restrict__ x, const float* __restrict__ delta,
                   const float* __restrict__ g, const float* __restrict__ bta,
                   unsigned short* __restrict__ xb_out)
{
    const int row = blockIdx.x;
    const int tid = threadIdx.x;
    float* xr = x + (size_t)row*D_;
    float4 xv = *(const float4*)(xr + tid*4);
    if (delta) {
        const float4 dv = *(const float4*)(delta + (size_t)row*D_ + tid*4);
        xv.x += dv.x; xv.y += dv.y; xv.z += dv.z; xv.w += dv.w;
    }
    float sum = xv.x + xv.y + xv.z + xv.w;
    float sq  = xv.x*xv.x + xv.y*xv.y + xv.z*xv.z + xv.w*xv.w;
    #pragma unroll
    for (int off = 1; off < 64; off <<= 1) {
        sum += __shfl_xor(sum, off, 64);
        sq  += __shfl_xor(sq,  off, 64);
    }
    __shared__ float red[2][2];
    if ((tid & 63) == 0) { red[tid >> 6][0] = sum; red[tid >> 6][1] = sq; }
    __syncthreads();
    sum = red[0][0] + red[1][0];
    sq  = red[0][1] + red[1][1];
    const float mu  = sum * (1.f/D_);
    const float var = sq * (1.f/D_) - mu*mu;
    const float rs  = rsqrtf(var + 1e-5f);
    const float4 gv = *(const float4*)(g   + tid*4);
    const float4 bv = *(const float4*)(bta + tid*4);
    float4 o;
    o.x = (xv.x - mu)*rs*gv.x + bv.x;
    o.y = (xv.y - mu)*rs*gv.y + bv.y;
    o.z = (xv.z - mu)*rs*gv.z + bv.z;
    o.w = (xv.w - mu)*rs*gv.w + bv.w;
    *(float4*)(xr + tid*4) = o;
    if (xb_out) {
        ushort4 u;
        u.x = f2bf(o.x); u.y = f2bf(o.y); u.z = f2bf(o.z); u.w = f2bf(o.w);
        *(ushort4*)(xb_out + (size_t)row*D_ + tid*4) = u;
    }
}

// ---------------------------------------------------------------------------
// Head: logits[T,5] = x[T,512] @ head_W[5,512]^T + head_b
// ---------------------------------------------------------------------------
__global__ __launch_bounds__(256)
void head_kernel(const float* __restrict__ x, const float* __restrict__ hw,
                 const float* __restrict__ hb, float* __restrict__ out)
{
    const int lane = threadIdx.x & 63;
    const int row  = blockIdx.x*4 + (threadIdx.x >> 6);
    const float* xr = x + (size_t)row*D_;
    float acc[C_] = {0.f,0.f,0.f,0.f,0.f};
    #pragma unroll
    for (int it = 0; it < D_/64; it++) {
        const int k0 = lane + it*64;
        const float xv = xr[k0];
        #pragma unroll
        for (int c = 0; c < C_; c++) acc[c] = fmaf(xv, hw[c*D_ + k0], acc[c]);
    }
    #pragma unroll
    for (int c = 0; c < C_; c++)
        #pragma unroll
        for (int off = 32; off; off >>= 1)
            acc[c] += __shfl_down(acc[c], off, 64);
    if (lane == 0) {
        #pragma unroll
        for (int c = 0; c < C_; c++) out[(size_t)row*C_ + c] = acc[c] + hb[c];
    }
}

// ---------------------------------------------------------------------------
__global__ __launch_bounds__(256)
void cast_bf16_kernel(const float* __restrict__ in, unsigned short* __restrict__ out, int n)
{
    const int i = (blockIdx.x*256 + threadIdx.x)*4;
    if (i < n) {
        const float4 v = *(const float4*)(in + i);
        ushort4 o;
        o.x = f2bf(v.x); o.y = f2bf(v.y); o.z = f2bf(v.z); o.w = f2bf(v.w);
        *(ushort4*)(out + i) = o;
    }
}

// cast Wq/Wk/Wv into packed [L][1536][512] bf16
__global__ __launch_bounds__(256)
void cast_qkv_kernel(const float* __restrict__ Wq, const float* __restrict__ Wk,
                     const float* __restrict__ Wv, unsigned short* __restrict__ dst)
{
    const int t  = blockIdx.y;          // 0..17
    const int ll = t / 3, wh = t % 3;
    const int DD = D_*D_;
    const float* srcs[3] = {Wq, Wk, Wv};
    const float* src = srcs[wh] + (size_t)ll*DD;
    unsigned short* d = dst + (size_t)ll*3*DD + (size_t)wh*DD;
    const int i = (blockIdx.x*256 + threadIdx.x)*4;
    if (i < DD) {
        const float4 v = *(const float4*)(src + i);
        ushort4 o;
        o.x = f2bf(v.x); o.y = f2bf(v.y); o.z = f2bf(v.z); o.w = f2bf(v.w);
        *(ushort4*)(d + i) = o;
    }
}

// concat per-layer qkv bias: [L][1536] f32
__global__ __launch_bounds__(256)
void qkv_bias_kernel(const float* __restrict__ bq, const float* __restrict__ bk,
                     const float* __restrict__ bv, float* __restrict__ dst)
{
    const int idx = blockIdx.x*256 + threadIdx.x;   // < 6*1536
    const int ll = idx / 1536, c = idx % 1536;
    float v;
    if (c < 512)       v = bq[ll*512 + c];
    else if (c < 1024) v = bk[ll*512 + c - 512];
    else               v = bv[ll*512 + c - 1024];
    dst[idx] = v;
}

// ---------------------------------------------------------------------------
extern "C" void kernel_launch(void* const* d_in, const int* in_sizes, int n_in,
                              void* d_out, int out_size, void* d_ws, size_t ws_size,
                              hipStream_t stream)
{
    const float* src     = (const float*)d_in[0];
    const unsigned char* kpm = (const unsigned char*)d_in[1];
    const float* embed_W = (const float*)d_in[2];
    const float* embed_b = (const float*)d_in[3];
    const float* Wq = (const float*)d_in[4];
    const float* bq = (const float*)d_in[5];
    const float* Wk = (const float*)d_in[6];
    const float* bk = (const float*)d_in[7];
    const float* Wv = (const float*)d_in[8];
    const float* bv = (const float*)d_in[9];
    const float* Wo = (const float*)d_in[10];
    const float* bo = (const float*)d_in[11];
    const float* W1 = (const float*)d_in[12];
    const float* b1 = (const float*)d_in[13];
    const float* W2 = (const float*)d_in[14];
    const float* b2 = (const float*)d_in[15];
    const float* ln1_g = (const float*)d_in[16];
    const float* ln1_b = (const float*)d_in[17];
    const float* ln2_g = (const float*)d_in[18];
    const float* ln2_b = (const float*)d_in[19];
    const float* fin_g = (const float*)d_in[20];
    const float* fin_b = (const float*)d_in[21];
    const float* head_W = (const float*)d_in[22];
    const float* head_b = (const float*)d_in[23];
    float* out = (float*)d_out;

    float* ws = (float*)d_ws;
    const size_t S = (size_t)T_ * D_;             // 4,194,304
    float* x   = ws;                               // [0,S) f32
    float* tmp = ws + S;                           // [S,2S) f32
    unsigned short* u16  = (unsigned short*)(ws + 2*S);
    unsigned short* xb   = u16;                    // S elems
    unsigned short* qkvb = u16 + 1*S;              // 3S elems: [T][1536]
    unsigned short* attb = u16 + 4*S;              // S elems
    unsigned short* h1b  = u16 + 1*S;              // 4S elems, aliases qkvb+attb (dead)
    unsigned short* wb   = u16 + 5*S;
    const int DD = D_*D_;
    const int DF = D_*FF_;
    unsigned short* wqkvb = wb;                    // 18*DD
    unsigned short* wob   = wb + 18*(size_t)DD;    // 6*DD
    unsigned short* w1b   = wb + 24*(size_t)DD;    // 24*DD
    unsigned short* w2b   = wb + 48*(size_t)DD;    // 24*DD
    float* qkvbias        = (float*)(wb + 72*(size_t)DD);  // 6*1536 f32

    const dim3 blk(256);
    const dim3 gE  (D_/64,    T_/128);             // fp32 embed grid
    const dim3 gQKV(1536/128, T_/128);             // fused qkv: 12 x 64
    const dim3 gN512(D_/64,   T_/128);             // BN=64 tile: 8 x 64 = 512 blocks
    const dim3 gMF (FF_/128,  T_/128);             // N=2048: 16 x 64

    // one-time weight prep
    cast_qkv_kernel<<<dim3(DD/1024, 18), blk, 0, stream>>>(Wq, Wk, Wv, wqkvb);
    cast_bf16_kernel<<<6*DD/1024, blk, 0, stream>>>(Wo, wob, 6*DD);
    cast_bf16_kernel<<<6*DF/1024, blk, 0, stream>>>(W1, w1b, 6*DF);
    cast_bf16_kernel<<<6*DF/1024, blk, 0, stream>>>(W2, w2b, 6*DF);
    qkv_bias_kernel<<<(6*1536)/256, blk, 0, stream>>>(bq, bk, bv, qkvbias);

    // embed (fp32) + bf16 copy
    gemm_bias_kernel<false><<<gE, blk, 0, stream>>>(src, embed_W, embed_b, x, T_, D_, DIN);
    cast_bf16_kernel<<<T_*D_/1024, blk, 0, stream>>>(x, xb, T_*D_);

    for (int l = 0; l < L_; l++) {
        const float* bol = bo + (size_t)l*D_;
        const float* b1l = b1 + (size_t)l*FF_;
        const float* b2l = b2 + (size_t)l*D_;

        // fused QKV projection -> qkvb [T][1536] bf16
        gemm_mfma_kernel<false,true,128><<<gQKV, blk, 0, stream>>>(xb, wqkvb + (size_t)l*3*DD,
                                                                   qkvbias + (size_t)l*1536, qkvb, T_, 1536, D_);

        attn_mfma_kernel<<<dim3(NSEQ/64, B_*H_), blk, 0, stream>>>(qkvb, kpm, attb);

        gemm_mfma_kernel<false,false,64><<<gN512, blk, 0, stream>>>(attb, wob + (size_t)l*DD, bol, tmp, T_, D_, D_);
        add_ln_kernel<<<T_, 128, 0, stream>>>(x, tmp, ln1_g + (size_t)l*D_, ln1_b + (size_t)l*D_, xb);

        gemm_mfma_kernel<true, true,128><<<gMF, blk, 0, stream>>>(xb, w1b + (size_t)l*DF, b1l, h1b, T_, FF_, D_);
        gemm_mfma_kernel<false,false,64><<<gN512, blk, 0, stream>>>(h1b, w2b + (size_t)l*DF, b2l, tmp, T_, D_, FF_);
        add_ln_kernel<<<T_, 128, 0, stream>>>(x, tmp, ln2_g + (size_t)l*D_, ln2_b + (size_t)l*D_, xb);
    }

    add_ln_kernel<<<T_, 128, 0, stream>>>(x, nullptr, fin_g, fin_b, nullptr);
    head_kernel<<<T_/4, 256, 0, stream>>>(x, head_W, head_b, out);
}

// Round 8
// 1094.601 us; speedup vs baseline: 5.7901x; 1.1623x over previous
//
#include <hip/hip_runtime.h>
#include <hip/hip_bf16.h>
#include <math.h>

#define B_   8
#define NSEQ 1024
#define T_   (B_*NSEQ)     // 8192 tokens
#define DIN  64
#define D_   512
#define H_   8
#define HD_  64
#define FF_  2048
#define L_   6
#define C_   5

typedef __attribute__((ext_vector_type(8))) short bf16x8;
typedef __attribute__((ext_vector_type(4))) float f32x4;

__device__ __forceinline__ unsigned short f2bf(float f) {
    __hip_bfloat16 h = __float2bfloat16(f);
    return *reinterpret_cast<unsigned short*>(&h);
}
__device__ __forceinline__ float bf2f(unsigned short u) {
    __hip_bfloat16 h = *reinterpret_cast<__hip_bfloat16*>(&u);
    return __bfloat162float(h);
}

__device__ __forceinline__ void gload_lds16(const void* g, void* l) {
    __builtin_amdgcn_global_load_lds(
        (const __attribute__((address_space(1))) unsigned int*)g,
        (__attribute__((address_space(3))) unsigned int*)l, 16, 0, 0);
}

// ---------------------------------------------------------------------------
// fp32 GEMM (embed only, K=64): C = A @ W^T + bias
// ---------------------------------------------------------------------------
template<bool RELU>
__global__ __launch_bounds__(256, 2)
void gemm_bias_kernel(const float* __restrict__ A, const float* __restrict__ W,
                      const float* __restrict__ bias, float* __restrict__ C,
                      int M, int N, int K)
{
    constexpr int BM = 128, BN = 64, BK = 16;
    __shared__ float As[BK][BM + 4];
    __shared__ float Ws[BK][BN + 4];
    const int tid = threadIdx.x;
    const int bm  = blockIdx.y * BM;
    const int bn  = blockIdx.x * BN;
    const int tm0 = (tid >> 4) * 4;
    const int tn0 = (tid & 15) * 4;

    float acc[8][4];
    #pragma unroll
    for (int i = 0; i < 8; i++)
        #pragma unroll
        for (int j = 0; j < 4; j++) acc[i][j] = 0.f;

    for (int k0 = 0; k0 < K; k0 += BK) {
        #pragma unroll
        for (int i = 0; i < 2; i++) {
            const int f  = tid + i*256;
            const int r  = f >> 2;
            const int kc = (f & 3) << 2;
            const float4 a4 = *(const float4*)(A + (size_t)(bm + r)*K + k0 + kc);
            As[kc+0][r] = a4.x; As[kc+1][r] = a4.y;
            As[kc+2][r] = a4.z; As[kc+3][r] = a4.w;
        }
        {
            const int r  = tid >> 2;
            const int kc = (tid & 3) << 2;
            const float4 w4 = *(const float4*)(W + (size_t)(bn + r)*K + k0 + kc);
            Ws[kc+0][r] = w4.x; Ws[kc+1][r] = w4.y;
            Ws[kc+2][r] = w4.z; Ws[kc+3][r] = w4.w;
        }
        __syncthreads();
        #pragma unroll
        for (int kk = 0; kk < BK; kk++) {
            const float4 a0 = *(const float4*)&As[kk][tm0];
            const float4 a1 = *(const float4*)&As[kk][tm0 + 64];
            const float4 w0 = *(const float4*)&Ws[kk][tn0];
            const float af[8] = {a0.x,a0.y,a0.z,a0.w,a1.x,a1.y,a1.z,a1.w};
            const float wf[4] = {w0.x,w0.y,w0.z,w0.w};
            #pragma unroll
            for (int i = 0; i < 8; i++)
                #pragma unroll
                for (int j = 0; j < 4; j++)
                    acc[i][j] = fmaf(af[i], wf[j], acc[i][j]);
        }
        __syncthreads();
    }

    const float4 b4 = *(const float4*)(bias + bn + tn0);
    const float bsv[4] = {b4.x, b4.y, b4.z, b4.w};
    #pragma unroll
    for (int i = 0; i < 8; i++) {
        const int r = bm + tm0 + (i & 3) + ((i >> 2) << 6);
        float o[4];
        #pragma unroll
        for (int j = 0; j < 4; j++) {
            float t = acc[i][j] + bsv[j];
            if (RELU) t = fmaxf(t, 0.f);
            o[j] = t;
        }
        *(float4*)(C + (size_t)r*N + bn + tn0) = *(const float4*)o;
    }
}

// ---------------------------------------------------------------------------
// bf16 MFMA GEMM, 2-phase double-buffered + bijective XCD swizzle (T1).
// BM=128, BK=64, BN template (128 or 64). 4 waves (2x2), 16x16x32 MFMA,
// XOR-swizzled LDS, global_load_lds staging overlapped with compute.
// Grid MUST have (gx*gy) % 8 == 0 (all our grids: 768/512/1024).
// ---------------------------------------------------------------------------
template<bool RELU, bool OUT_BF16, int BN>
__global__ __launch_bounds__(256, BN==64 ? 3 : 2)
void gemm_mfma_kernel(const unsigned short* __restrict__ A,
                      const unsigned short* __restrict__ W,
                      const float* __restrict__ bias,
                      void* __restrict__ Cout,
                      int M, int N, int K)
{
    constexpr int BM = 128, BK = 64;
    constexpr int NFN = BN/32;            // 4 (BN=128) or 2 (BN=64)
    __shared__ short As[2][BM*BK];
    __shared__ short Bs[2][BN*BK];
    const int tid = threadIdx.x;
    const int l   = tid & 63;
    const int wid = tid >> 6;
    const int wm  = wid >> 1, wn = wid & 1;

    // XCD swizzle: orig consecutive ids round-robin XCDs; remap so each XCD
    // owns a contiguous chunk of tiles (shares A row-panels in its L2).
    const int gx  = gridDim.x;
    const int nwg = gx * gridDim.y;
    int bid = blockIdx.y * gx + blockIdx.x;
    bid = (bid & 7) * (nwg >> 3) + (bid >> 3);
    const int bm = (bid / gx) * BM;
    const int bn = (bid % gx) * BN;

    const int srow = l >> 3;
    const int scol = ((l & 7) ^ srow) * 8;

    f32x4 acc[4][NFN];
    const f32x4 z = {0.f, 0.f, 0.f, 0.f};
    #pragma unroll
    for (int m = 0; m < 4; m++)
        #pragma unroll
        for (int n = 0; n < NFN; n++) acc[m][n] = z;

    const int nk = K / BK;

    auto stage = [&](int kt, int sb) {
        const int k0 = kt * BK;
        #pragma unroll
        for (int c = 0; c < 4; c++) {
            const int r = wid*32 + c*8 + srow;
            gload_lds16(A + (size_t)(bm + r)*K + k0 + scol, &As[sb][(wid*32 + c*8)*64]);
        }
        #pragma unroll
        for (int c = 0; c < BN/32; c++) {
            const int r = wid*(BN/4) + c*8 + srow;
            gload_lds16(W + (size_t)(bn + r)*K + k0 + scol, &Bs[sb][(wid*(BN/4) + c*8)*64]);
        }
    };

    stage(0, 0);
    int buf = 0;
    for (int kt = 0; kt < nk; kt++) {
        __syncthreads();   // drains stage(kt) (compiler vmcnt0)
        if (kt + 1 < nk) stage(kt + 1, buf ^ 1);   // in flight under compute(kt)

        #pragma unroll
        for (int h = 0; h < 2; h++) {
            bf16x8 af[4], bfr[NFN];
            #pragma unroll
            for (int m = 0; m < 4; m++) {
                const int R  = wm*64 + m*16 + (l & 15);
                const int cb = (h*64 + (l >> 4)*16) ^ ((R & 7) << 4);
                af[m] = *(const bf16x8*)((const char*)&As[buf][0] + R*128 + cb);
            }
            #pragma unroll
            for (int n = 0; n < NFN; n++) {
                const int Rc = wn*(BN/2) + n*16 + (l & 15);
                const int cb = (h*64 + (l >> 4)*16) ^ ((Rc & 7) << 4);
                bfr[n] = *(const bf16x8*)((const char*)&Bs[buf][0] + Rc*128 + cb);
            }
            #pragma unroll
            for (int m = 0; m < 4; m++)
                #pragma unroll
                for (int n = 0; n < NFN; n++)
                    acc[m][n] = __builtin_amdgcn_mfma_f32_16x16x32_bf16(af[m], bfr[n], acc[m][n], 0, 0, 0);
        }
        buf ^= 1;
    }

    #pragma unroll
    for (int n = 0; n < NFN; n++) {
        const int col = bn + wn*(BN/2) + n*16 + (l & 15);
        const float bv = bias[col];
        #pragma unroll
        for (int m = 0; m < 4; m++) {
            const int row0 = bm + wm*64 + m*16 + ((l >> 4) << 2);
            #pragma unroll
            for (int j = 0; j < 4; j++) {
                float t = acc[m][n][j] + bv;
                if (RELU) t = fmaxf(t, 0.f);
                if (OUT_BF16)
                    ((unsigned short*)Cout)[(size_t)(row0 + j)*N + col] = f2bf(t);
                else
                    ((float*)Cout)[(size_t)(row0 + j)*N + col] = t;
            }
        }
    }
}

// ---------------------------------------------------------------------------
// bf16 MFMA flash attention v4: 4 waves x 32 q-rows = 128 q-rows/block.
// KV tile 64, K dbuf via global_load_lds (XOR-swizzle), V dbuf reg-staged,
// swapped QK^T, in-lane softmax, setprio around MFMA clusters.
// ---------------------------------------------------------------------------
__global__ __launch_bounds__(256, 2)
void attn_mfma_kernel(const unsigned short* __restrict__ QKV,
                      const unsigned char* __restrict__ mask,
                      unsigned short* __restrict__ O)
{
    constexpr int QS = 1536;
    __shared__ short Ks[2][64*64];   // K tiles, linear 128B rows, XOR-swizzled
    __shared__ short Vt[2][64*72];   // V transposed [d][kv], pitch 72
    __shared__ short Ps[4][32*72];   // per-wave P [32 q][kv], pitch 72
    const int tid = threadIdx.x;
    const int l   = tid & 63;
    const int w   = tid >> 6;
    const int g   = l >> 4;          // lane group 0..3
    const int q16 = l & 15;
    const int b   = blockIdx.y >> 3;
    const int h   = blockIdx.y & 7;
    const int q0  = blockIdx.x * 128;
    const int qb  = q0 + w*32;       // wave's 32 q-rows
    const size_t tokbase = (size_t)b * NSEQ;

    // Q fragments (B-operand): frag qf covers q-rows qb+qf*16+q16
    bf16x8 bq[2][2];
    #pragma unroll
    for (int qf = 0; qf < 2; qf++) {
        const unsigned short* qp = QKV + (tokbase + qb + qf*16 + q16)*QS + h*HD_ + g*8;
        bq[qf][0] = *(const bf16x8*)qp;
        bq[qf][1] = *(const bf16x8*)(qp + 32);
    }

    f32x4 accO[2][4];
    const f32x4 z = {0.f,0.f,0.f,0.f};
    #pragma unroll
    for (int qf = 0; qf < 2; qf++)
        #pragma unroll
        for (int n = 0; n < 4; n++) accO[qf][n] = z;
    float mrow[2] = {-INFINITY, -INFINITY};
    float lrow[2] = {0.f, 0.f};

    const int srow = l >> 3;
    const int scol = ((l & 7) ^ srow) * 8;
    const unsigned char* mp = mask + (size_t)b*NSEQ;

    // prologue: stage K(0); load+store V(0)
    #pragma unroll
    for (int c = 0; c < 2; c++) {
        const int rb = (w*2 + c)*8;
        gload_lds16(QKV + (tokbase + rb + srow)*QS + D_ + h*HD_ + scol, &Ks[0][rb*64]);
    }
    {
        const unsigned short* vp = QKV + (tokbase + l)*QS + 2*D_ + h*HD_ + w*16;
        const bf16x8 v8a = *(const bf16x8*)vp;
        const bf16x8 v8b = *(const bf16x8*)(vp + 8);
        #pragma unroll
        for (int j = 0; j < 8; j++) {
            Vt[0][(w*16 + j)*72 + l]     = v8a[j];
            Vt[0][(w*16 + 8 + j)*72 + l] = v8b[j];
        }
    }

    for (int t = 0; t < NSEQ/64; t++) {
        const int buf = t & 1;
        const int kv0 = t*64;
        __syncthreads();   // stage(t)+V-writes(t) visible; prev reads of buf^1 done

        // issue stage(t+1): K -> Ks[buf^1], V -> regs (write late)
        bf16x8 nva, nvb;
        const bool more = (t + 1 < NSEQ/64);
        if (more) {
            const int kvn = kv0 + 64;
            #pragma unroll
            for (int c = 0; c < 2; c++) {
                const int rb = (w*2 + c)*8;
                gload_lds16(QKV + (tokbase + kvn + rb + srow)*QS + D_ + h*HD_ + scol,
                            &Ks[buf^1][rb*64]);
            }
            const unsigned short* vp = QKV + (tokbase + kvn + l)*QS + 2*D_ + h*HD_ + w*16;
            nva = *(const bf16x8*)vp;
            nvb = *(const bf16x8*)(vp + 8);
        }

        // QK^T swapped: s4[qf][n][r] = S[kv=16n+4g+r][q = qb+qf*16+q16]
        f32x4 s4[2][4];
        #pragma unroll
        for (int qf = 0; qf < 2; qf++)
            #pragma unroll
            for (int n = 0; n < 4; n++) s4[qf][n] = z;
        __builtin_amdgcn_s_setprio(1);
        #pragma unroll
        for (int ks = 0; ks < 2; ks++) {
            const int cb = (ks*64 + g*16) ^ ((q16 & 7) << 4);
            bf16x8 ak[4];
            #pragma unroll
            for (int n = 0; n < 4; n++)
                ak[n] = *(const bf16x8*)((const char*)&Ks[buf][0] + (n*16 + q16)*128 + cb);
            #pragma unroll
            for (int qf = 0; qf < 2; qf++)
                #pragma unroll
                for (int n = 0; n < 4; n++)
                    s4[qf][n] = __builtin_amdgcn_mfma_f32_16x16x32_bf16(ak[n], bq[qf][ks], s4[qf][n], 0, 0, 0);
        }
        __builtin_amdgcn_s_setprio(0);

        const unsigned long long mbits = __ballot(mp[kv0 + l] != 0);

        // softmax per q-frag (in-lane over 16 kv + 2 shfl_xor across groups)
        #pragma unroll
        for (int qf = 0; qf < 2; qf++) {
            float sv[4][4];
            #pragma unroll
            for (int n = 0; n < 4; n++)
                #pragma unroll
                for (int r = 0; r < 4; r++) sv[n][r] = s4[qf][n][r]*0.125f;
            if (mbits) {   // wave-uniform; skipped for all-false mask
                #pragma unroll
                for (int n = 0; n < 4; n++)
                    #pragma unroll
                    for (int r = 0; r < 4; r++)
                        if ((mbits >> (unsigned)(16*n + 4*g + r)) & 1ULL) sv[n][r] = -INFINITY;
            }
            float tmax = sv[0][0];
            #pragma unroll
            for (int n = 0; n < 4; n++)
                #pragma unroll
                for (int r = 0; r < 4; r++) tmax = fmaxf(tmax, sv[n][r]);
            tmax = fmaxf(tmax, __shfl_xor(tmax, 16));
            tmax = fmaxf(tmax, __shfl_xor(tmax, 32));
            const float mnew  = fmaxf(mrow[qf], tmax);
            const float alpha = __expf(mrow[qf] - mnew);
            float rs = 0.f;
            unsigned int pw[4][2];
            #pragma unroll
            for (int n = 0; n < 4; n++) {
                const unsigned short p0 = f2bf(__expf(sv[n][0] - mnew));
                const unsigned short p1 = f2bf(__expf(sv[n][1] - mnew));
                const unsigned short p2 = f2bf(__expf(sv[n][2] - mnew));
                const unsigned short p3 = f2bf(__expf(sv[n][3] - mnew));
                pw[n][0] = (unsigned)p0 | ((unsigned)p1 << 16);
                pw[n][1] = (unsigned)p2 | ((unsigned)p3 << 16);
                rs += bf2f(p0) + bf2f(p1) + bf2f(p2) + bf2f(p3);  // sum ROUNDED p
            }
            rs += __shfl_xor(rs, 16);
            rs += __shfl_xor(rs, 32);
            lrow[qf] = lrow[qf]*alpha + rs;
            mrow[qf] = mnew;

            float alr[4];
            #pragma unroll
            for (int r = 0; r < 4; r++) alr[r] = __shfl(alpha, g*4 + r, 16);
            #pragma unroll
            for (int n = 0; n < 4; n++)
                #pragma unroll
                for (int r = 0; r < 4; r++) accO[qf][n][r] *= alr[r];

            // P -> LDS row qf*16+q16, kv slots 16n+4g..+3
            #pragma unroll
            for (int n = 0; n < 4; n++) {
                uint2 u; u.x = pw[n][0]; u.y = pw[n][1];
                *(uint2*)&Ps[w][(qf*16 + q16)*72 + 16*n + 4*g] = u;
            }
        }

        // PV: accO[qf][n][r] for q'=qf*16+4g+r, d=16n+q16
        __builtin_amdgcn_s_setprio(1);
        #pragma unroll
        for (int ks = 0; ks < 2; ks++) {
            const bf16x8 ap0 = *(const bf16x8*)&Ps[w][(q16)*72      + ks*32 + g*8];
            const bf16x8 ap1 = *(const bf16x8*)&Ps[w][(16 + q16)*72 + ks*32 + g*8];
            #pragma unroll
            for (int n = 0; n < 4; n++) {
                const bf16x8 bv = *(const bf16x8*)&Vt[buf][(n*16 + q16)*72 + ks*32 + g*8];
                accO[0][n] = __builtin_amdgcn_mfma_f32_16x16x32_bf16(ap0, bv, accO[0][n], 0, 0, 0);
                accO[1][n] = __builtin_amdgcn_mfma_f32_16x16x32_bf16(ap1, bv, accO[1][n], 0, 0, 0);
            }
        }
        __builtin_amdgcn_s_setprio(0);

        // write V(t+1) into Vt[buf^1]
        if (more) {
            #pragma unroll
            for (int j = 0; j < 8; j++) {
                Vt[buf^1][(w*16 + j)*72 + l]     = nva[j];
                Vt[buf^1][(w*16 + 8 + j)*72 + l] = nvb[j];
            }
        }
    }

    // epilogue
    #pragma unroll
    for (int qf = 0; qf < 2; qf++) {
        float linv[4];
        #pragma unroll
        for (int r = 0; r < 4; r++) linv[r] = 1.0f / __shfl(lrow[qf], g*4 + r, 16);
        #pragma unroll
        for (int r = 0; r < 4; r++) {
            unsigned short* op = O + (tokbase + qb + qf*16 + 4*g + r)*D_ + h*HD_;
            #pragma unroll
            for (int n = 0; n < 4; n++)
                op[16*n + q16] = f2bf(accO[qf][n][r] * linv[r]);
        }
    }
}

// ---------------------------------------------------------------------------
// Fused (x += delta_bf16); LayerNorm; optional bf16 copy out.
// ---------------------------------------------------------------------------
__global__ __launch_bounds__(128)
void add_ln_kernel(float* __restrict__ x, const unsigned short* __restrict__ delta,
                   const float* __restrict__ g, const float* __restrict__ bta,
                   unsigned short* __restrict__ xb_out)
{
    const int row = blockIdx.x;
    const int tid = threadIdx.x;
    float* xr = x + (size_t)row*D_;
    float4 xv = *(const float4*)(xr + tid*4);
    if (delta) {
        const ushort4 dv = *(const ushort4*)(delta + (size_t)row*D_ + tid*4);
        xv.x += bf2f(dv.x); xv.y += bf2f(dv.y); xv.z += bf2f(dv.z); xv.w += bf2f(dv.w);
    }
    float sum = xv.x + xv.y + xv.z + xv.w;
    float sq  = xv.x*xv.x + xv.y*xv.y + xv.z*xv.z + xv.w*xv.w;
    #pragma unroll
    for (int off = 1; off < 64; off <<= 1) {
        sum += __shfl_xor(sum, off, 64);
        sq  += __shfl_xor(sq,  off, 64);
    }
    __shared__ float red[2][2];
    if ((tid & 63) == 0) { red[tid >> 6][0] = sum; red[tid >> 6][1] = sq; }
    __syncthreads();
    sum = red[0][0] + red[1][0];
    sq  = red[0][1] + red[1][1];
    const float mu  = sum * (1.f/D_);
    const float var = sq * (1.f/D_) - mu*mu;
    const float rs  = rsqrtf(var + 1e-5f);
    const float4 gv = *(const float4*)(g   + tid*4);
    const float4 bv = *(const float4*)(bta + tid*4);
    float4 o;
    o.x = (xv.x - mu)*rs*gv.x + bv.x;
    o.y = (xv.y - mu)*rs*gv.y + bv.y;
    o.z = (xv.z - mu)*rs*gv.z + bv.z;
    o.w = (xv.w - mu)*rs*gv.w + bv.w;
    *(float4*)(xr + tid*4) = o;
    if (xb_out) {
        ushort4 u;
        u.x = f2bf(o.x); u.y = f2bf(o.y); u.z = f2bf(o.z); u.w = f2bf(o.w);
        *(ushort4*)(xb_out + (size_t)row*D_ + tid*4) = u;
    }
}

// ---------------------------------------------------------------------------
// Head: logits[T,5] = x[T,512] @ head_W[5,512]^T + head_b
// ---------------------------------------------------------------------------
__global__ __launch_bounds__(256)
void head_kernel(const float* __restrict__ x, const float* __restrict__ hw,
                 const float* __restrict__ hb, float* __restrict__ out)
{
    const int lane = threadIdx.x & 63;
    const int row  = blockIdx.x*4 + (threadIdx.x >> 6);
    const float* xr = x + (size_t)row*D_;
    float acc[C_] = {0.f,0.f,0.f,0.f,0.f};
    #pragma unroll
    for (int it = 0; it < D_/64; it++) {
        const int k0 = lane + it*64;
        const float xv = xr[k0];
        #pragma unroll
        for (int c = 0; c < C_; c++) acc[c] = fmaf(xv, hw[c*D_ + k0], acc[c]);
    }
    #pragma unroll
    for (int c = 0; c < C_; c++)
        #pragma unroll
        for (int off = 32; off; off >>= 1)
            acc[c] += __shfl_down(acc[c], off, 64);
    if (lane == 0) {
        #pragma unroll
        for (int c = 0; c < C_; c++) out[(size_t)row*C_ + c] = acc[c] + hb[c];
    }
}

// ---------------------------------------------------------------------------
__global__ __launch_bounds__(256)
void cast_bf16_kernel(const float* __restrict__ in, unsigned short* __restrict__ out, int n)
{
    const int i = (blockIdx.x*256 + threadIdx.x)*4;
    if (i < n) {
        const float4 v = *(const float4*)(in + i);
        ushort4 o;
        o.x = f2bf(v.x); o.y = f2bf(v.y); o.z = f2bf(v.z); o.w = f2bf(v.w);
        *(ushort4*)(out + i) = o;
    }
}

// cast Wq/Wk/Wv into packed [L][1536][512] bf16
__global__ __launch_bounds__(256)
void cast_qkv_kernel(const float* __restrict__ Wq, const float* __restrict__ Wk,
                     const float* __restrict__ Wv, unsigned short* __restrict__ dst)
{
    const int t  = blockIdx.y;          // 0..17
    const int ll = t / 3, wh = t % 3;
    const int DD = D_*D_;
    const float* srcs[3] = {Wq, Wk, Wv};
    const float* src = srcs[wh] + (size_t)ll*DD;
    unsigned short* d = dst + (size_t)ll*3*DD + (size_t)wh*DD;
    const int i = (blockIdx.x*256 + threadIdx.x)*4;
    if (i < DD) {
        const float4 v = *(const float4*)(src + i);
        ushort4 o;
        o.x = f2bf(v.x); o.y = f2bf(v.y); o.z = f2bf(v.z); o.w = f2bf(v.w);
        *(ushort4*)(d + i) = o;
    }
}

// concat per-layer qkv bias: [L][1536] f32
__global__ __launch_bounds__(256)
void qkv_bias_kernel(const float* __restrict__ bq, const float* __restrict__ bk,
                     const float* __restrict__ bv, float* __restrict__ dst)
{
    const int idx = blockIdx.x*256 + threadIdx.x;   // < 6*1536
    const int ll = idx / 1536, c = idx % 1536;
    float v;
    if (c < 512)       v = bq[ll*512 + c];
    else if (c < 1024) v = bk[ll*512 + c - 512];
    else               v = bv[ll*512 + c - 1024];
    dst[idx] = v;
}

// ---------------------------------------------------------------------------
extern "C" void kernel_launch(void* const* d_in, const int* in_sizes, int n_in,
                              void* d_out, int out_size, void* d_ws, size_t ws_size,
                              hipStream_t stream)
{
    const float* src     = (const float*)d_in[0];
    const unsigned char* kpm = (const unsigned char*)d_in[1];
    const float* embed_W = (const float*)d_in[2];
    const float* embed_b = (const float*)d_in[3];
    const float* Wq = (const float*)d_in[4];
    const float* bq = (const float*)d_in[5];
    const float* Wk = (const float*)d_in[6];
    const float* bk = (const float*)d_in[7];
    const float* Wv = (const float*)d_in[8];
    const float* bv = (const float*)d_in[9];
    const float* Wo = (const float*)d_in[10];
    const float* bo = (const float*)d_in[11];
    const float* W1 = (const float*)d_in[12];
    const float* b1 = (const float*)d_in[13];
    const float* W2 = (const float*)d_in[14];
    const float* b2 = (const float*)d_in[15];
    const float* ln1_g = (const float*)d_in[16];
    const float* ln1_b = (const float*)d_in[17];
    const float* ln2_g = (const float*)d_in[18];
    const float* ln2_b = (const float*)d_in[19];
    const float* fin_g = (const float*)d_in[20];
    const float* fin_b = (const float*)d_in[21];
    const float* head_W = (const float*)d_in[22];
    const float* head_b = (const float*)d_in[23];
    float* out = (float*)d_out;

    float* ws = (float*)d_ws;
    const size_t S = (size_t)T_ * D_;             // 4,194,304
    float* x = ws;                                 // [0,S) f32
    unsigned short* u16  = (unsigned short*)(ws + S);
    unsigned short* xb   = u16;                    // S elems
    unsigned short* qkvb = u16 + 1*S;              // 3S elems: [T][1536]
    unsigned short* attb = u16 + 4*S;              // S elems
    unsigned short* tmpb = u16 + 5*S;              // S elems (bf16 deltas)
    unsigned short* h1b  = u16 + 1*S;              // 4S elems, aliases qkvb+attb (dead)
    unsigned short* wb   = u16 + 6*S;
    const int DD = D_*D_;
    const int DF = D_*FF_;
    unsigned short* wqkvb = wb;                    // 18*DD
    unsigned short* wob   = wb + 18*(size_t)DD;    // 6*DD
    unsigned short* w1b   = wb + 24*(size_t)DD;    // 24*DD
    unsigned short* w2b   = wb + 48*(size_t)DD;    // 24*DD
    float* qkvbias        = (float*)(wb + 72*(size_t)DD);  // 6*1536 f32

    const dim3 blk(256);
    const dim3 gE  (D_/64,    T_/128);             // fp32 embed grid
    const dim3 gQKV(1536/128, T_/128);             // 12 x 64 = 768 blocks (%8==0)
    const dim3 gN512(D_/64,   T_/128);             // 8 x 64  = 512 blocks (%8==0)
    const dim3 gMF (FF_/128,  T_/128);             // 16 x 64 = 1024 blocks (%8==0)

    // one-time weight prep
    cast_qkv_kernel<<<dim3(DD/1024, 18), blk, 0, stream>>>(Wq, Wk, Wv, wqkvb);
    cast_bf16_kernel<<<6*DD/1024, blk, 0, stream>>>(Wo, wob, 6*DD);
    cast_bf16_kernel<<<6*DF/1024, blk, 0, stream>>>(W1, w1b, 6*DF);
    cast_bf16_kernel<<<6*DF/1024, blk, 0, stream>>>(W2, w2b, 6*DF);
    qkv_bias_kernel<<<(6*1536)/256, blk, 0, stream>>>(bq, bk, bv, qkvbias);

    // embed (fp32) + bf16 copy
    gemm_bias_kernel<false><<<gE, blk, 0, stream>>>(src, embed_W, embed_b, x, T_, D_, DIN);
    cast_bf16_kernel<<<T_*D_/1024, blk, 0, stream>>>(x, xb, T_*D_);

    for (int l = 0; l < L_; l++) {
        const float* bol = bo + (size_t)l*D_;
        const float* b1l = b1 + (size_t)l*FF_;
        const float* b2l = b2 + (size_t)l*D_;

        // fused QKV projection -> qkvb [T][1536] bf16
        gemm_mfma_kernel<false,true,128><<<gQKV, blk, 0, stream>>>(xb, wqkvb + (size_t)l*3*DD,
                                                                   qkvbias + (size_t)l*1536, qkvb, T_, 1536, D_);

        attn_mfma_kernel<<<dim3(NSEQ/128, B_*H_), blk, 0, stream>>>(qkvb, kpm, attb);

        gemm_mfma_kernel<false,true,64><<<gN512, blk, 0, stream>>>(attb, wob + (size_t)l*DD, bol, tmpb, T_, D_, D_);
        add_ln_kernel<<<T_, 128, 0, stream>>>(x, tmpb, ln1_g + (size_t)l*D_, ln1_b + (size_t)l*D_, xb);

        gemm_mfma_kernel<true, true,128><<<gMF, blk, 0, stream>>>(xb, w1b + (size_t)l*DF, b1l, h1b, T_, FF_, D_);
        gemm_mfma_kernel<false,true,64><<<gN512, blk, 0, stream>>>(h1b, w2b + (size_t)l*DF, b2l, tmpb, T_, D_, FF_);
        add_ln_kernel<<<T_, 128, 0, stream>>>(x, tmpb, ln2_g + (size_t)l*D_, ln2_b + (size_t)l*D_, xb);
    }

    add_ln_kernel<<<T_, 128, 0, stream>>>(x, nullptr, fin_g, fin_b, nullptr);
    head_kernel<<<T_/4, 256, 0, stream>>>(x, head_W, head_b, out);
}